// Round 4
// baseline (1078.581 us; speedup 1.0000x reference)
//
#include <hip/hip_runtime.h>

#define NC 100000
#define NA 1024
#define FA 4096

// ---------------- art[i] = article_x . W_lin1[i] + b_lin1[i] ----------------
__global__ void k_art(const float* __restrict__ ax, const float* __restrict__ W,
                      const float* __restrict__ b, float* __restrict__ art) {
    int wave = (blockIdx.x * blockDim.x + threadIdx.x) >> 6;
    int lane = threadIdx.x & 63;
    if (wave >= NA) return;
    const float* wr = W + (size_t)wave * FA;
    float s = 0.f;
    #pragma unroll
    for (int i = 0; i < FA; i += 256) {
        float4 a  = *(const float4*)&ax[i + 4 * lane];
        float4 wv = *(const float4*)&wr[i + 4 * lane];
        s += a.x * wv.x + a.y * wv.y + a.z * wv.z + a.w * wv.w;
    }
    for (int off = 32; off; off >>= 1) s += __shfl_down(s, off);
    if (lane == 0) art[wave] = s + b[wave];
}

// ---------------- scalar scatter: agg[dst] += art[src]; cnt[dst] += 1 ----------------
__global__ void k_edge_scalar(const int* __restrict__ ei, int E,
                              const float* __restrict__ art,
                              float* __restrict__ agg, float* __restrict__ cnt) {
    int t = blockIdx.x * blockDim.x + threadIdx.x;
    int stride = gridDim.x * blockDim.x;
    for (int e = t; e < E; e += stride) {
        int s = ei[e], d = ei[E + e];
        atomicAdd(&agg[d], art[s]);
        atomicAdd(&cnt[d], 1.0f);
    }
}

// ---------------- CSR build: histogram ----------------
__global__ void k_hist(const int* __restrict__ ei, int E, int* __restrict__ deg) {
    int t = blockIdx.x * blockDim.x + threadIdx.x;
    int stride = gridDim.x * blockDim.x;
    for (int e = t; e < E; e += stride) atomicAdd(&deg[ei[E + e]], 1);
}

// ---------------- CSR build: scan stage 1 ----------------
__global__ void k_scan1(const int* __restrict__ deg, int* __restrict__ pre,
                        int* __restrict__ blksum) {
    __shared__ int ts[256];
    int base = blockIdx.x * 1024 + threadIdx.x * 4;
    int v0 = 0, v1 = 0, v2 = 0, v3 = 0;
    if (base + 0 < NC) v0 = deg[base + 0];
    if (base + 1 < NC) v1 = deg[base + 1];
    if (base + 2 < NC) v2 = deg[base + 2];
    if (base + 3 < NC) v3 = deg[base + 3];
    int tsum = v0 + v1 + v2 + v3;
    ts[threadIdx.x] = tsum;
    __syncthreads();
    for (int off = 1; off < 256; off <<= 1) {
        int y = (threadIdx.x >= off) ? ts[threadIdx.x - off] : 0;
        __syncthreads();
        ts[threadIdx.x] += y;
        __syncthreads();
    }
    int excl = ts[threadIdx.x] - tsum;
    if (base + 0 < NC) pre[base + 0] = excl;
    if (base + 1 < NC) pre[base + 1] = excl + v0;
    if (base + 2 < NC) pre[base + 2] = excl + v0 + v1;
    if (base + 3 < NC) pre[base + 3] = excl + v0 + v1 + v2;
    if (threadIdx.x == 255) blksum[blockIdx.x] = ts[255];
}

// ---------------- CSR build: scan stage 2 ----------------
__global__ void k_scan2(int* __restrict__ blksum, int NB) {
    __shared__ int ts[256];
    int v = (threadIdx.x < NB) ? blksum[threadIdx.x] : 0;
    ts[threadIdx.x] = v;
    __syncthreads();
    for (int off = 1; off < 256; off <<= 1) {
        int y = (threadIdx.x >= off) ? ts[threadIdx.x - off] : 0;
        __syncthreads();
        ts[threadIdx.x] += y;
        __syncthreads();
    }
    if (threadIdx.x < NB) blksum[threadIdx.x] = ts[threadIdx.x] - v;  // exclusive
}

// ---------------- CSR build: scan stage 3 ----------------
__global__ void k_scan3(const int* __restrict__ pre, const int* __restrict__ blksum,
                        const int* __restrict__ deg, int* __restrict__ off,
                        int* __restrict__ cursor, float* __restrict__ cntf) {
    int i = blockIdx.x * blockDim.x + threadIdx.x;
    if (i < NC) {
        int o = pre[i] + blksum[i >> 10];
        off[i] = o;
        cursor[i] = o;
        cntf[i] = (float)deg[i];
    }
}

// ---------------- CSR build: scatter (src, edge-id) ----------------
__global__ void k_csr_scatter(const int* __restrict__ ei, int E,
                              int* __restrict__ cursor, int* __restrict__ srcs,
                              int* __restrict__ eidx) {
    int t = blockIdx.x * blockDim.x + threadIdx.x;
    int stride = gridDim.x * blockDim.x;
    for (int e = t; e < E; e += stride) {
        int s = ei[e], d = ei[E + e];
        int p = atomicAdd(&cursor[d], 1);
        srcs[p] = s;
        eidx[p] = e;
    }
}

// ---------------- CSR aggregate ----------------
__global__ __launch_bounds__(256)
void k_csr_agg(const int* __restrict__ off, const int* __restrict__ deg,
               const int* __restrict__ srcs, const float* __restrict__ h,
               float* __restrict__ agg) {
    int node = (blockIdx.x * blockDim.x + threadIdx.x) >> 6;
    int lane = threadIdx.x & 63;
    if (node >= NC) return;
    int b = off[node], d = deg[node];
    float sx = 0.f, sy = 0.f;
    for (int j = 0; j < d; ++j) {
        int src = srcs[b + j];
        float2 m = *(const float2*)&h[(size_t)src * 128 + 2 * lane];
        sx += m.x; sy += m.y;
    }
    float2 r = make_float2(sx, sy);
    *(float2*)&agg[(size_t)node * 128 + 2 * lane] = r;
}

// ---------------- GEMM: out[i][f] = act(X1[i].W1[f] (+/cnt) + X2[i].W2[f] + ...) ----------------
// W layout: original [128 out][K in] row-major with row stride lda (lane loads float4 of k).
// Block: 256 threads = 4 waves; 128 rows/block, wave w owns rows [32w,32w+32); lane owns
// cols {lane, lane+64}. LDS: k-major xs[64][132] staged conflict-free (2-way), reads broadcast.
template<bool TWO, bool RELU, bool SCAL, bool BIAS>
__global__ __launch_bounds__(256, 3)
void k_gemm2(const float* __restrict__ X1, int K1,
             const float* __restrict__ W1, int lda1,
             const float* __restrict__ X2, int K2,
             const float* __restrict__ W2, int lda2,
             const float* __restrict__ bias,
             const float* __restrict__ aggS, const float* __restrict__ cntS,
             const float* __restrict__ wlcol, const float* __restrict__ rcnt,
             float* __restrict__ out, int N)
{
    __shared__ float xs[64 * 132];
    const int t = threadIdx.x;
    const int lane = t & 63;
    const int w = t >> 6;
    const int rowbase = blockIdx.x * 128;

    float acc0[32], acc1[32];
    #pragma unroll
    for (int r = 0; r < 32; ++r) { acc0[r] = 0.f; acc1[r] = 0.f; }

    const int nt1 = K1 >> 6;
    const int nt = TWO ? nt1 + (K2 >> 6) : nt1;

    float4 pf[8];

    // tile 0 load + store
    {
        #pragma unroll
        for (int it = 0; it < 8; ++it) {
            int srow = ((it << 6) + (t >> 2)) & 127;
            int skq = (t & 3) + ((it >> 1) << 2);
            int row = rowbase + srow;
            pf[it] = make_float4(0.f, 0.f, 0.f, 0.f);
            if (row < N) pf[it] = *(const float4*)&X1[(size_t)row * K1 + 4 * skq];
        }
        #pragma unroll
        for (int it = 0; it < 8; ++it) {
            int srow = ((it << 6) + (t >> 2)) & 127;
            int skq = (t & 3) + ((it >> 1) << 2);
            float* d = &xs[(4 * skq) * 132 + srow];
            d[0] = pf[it].x; d[132] = pf[it].y; d[264] = pf[it].z; d[396] = pf[it].w;
        }
    }
    __syncthreads();

    for (int tile = 0; tile < nt; ++tile) {
        const bool hasNext = (tile + 1) < nt;
        if (hasNext) {
            int tn = tile + 1;
            const float* Xp; int xst, ko;
            if (!TWO || tn < nt1) { Xp = X1; xst = K1; ko = tn << 6; }
            else { Xp = X2; xst = K2; ko = (tn - nt1) << 6; }
            #pragma unroll
            for (int it = 0; it < 8; ++it) {
                int srow = ((it << 6) + (t >> 2)) & 127;
                int skq = (t & 3) + ((it >> 1) << 2);
                int row = rowbase + srow;
                pf[it] = make_float4(0.f, 0.f, 0.f, 0.f);
                if (row < N) pf[it] = *(const float4*)&Xp[(size_t)row * xst + ko + 4 * skq];
            }
        }

        const float* Wp; int ld, ko;
        if (!TWO || tile < nt1) { Wp = W1; ld = lda1; ko = tile << 6; }
        else { Wp = W2; ld = lda2; ko = (tile - nt1) << 6; }
        const float* w0p = &Wp[(size_t)lane * ld + ko];
        const float* w1p = &Wp[(size_t)(lane + 64) * ld + ko];
        const float* xb = &xs[w << 5];

        #pragma unroll 2
        for (int kk = 0; kk < 64; kk += 4) {
            float4 wv0 = *(const float4*)&w0p[kk];
            float4 wv1 = *(const float4*)&w1p[kk];
            const float* wf0 = (const float*)&wv0;
            const float* wf1 = (const float*)&wv1;
            #pragma unroll
            for (int j = 0; j < 4; ++j) {
                const float* xk = &xb[(kk + j) * 132];
                float a = wf0[j], b = wf1[j];
                #pragma unroll
                for (int q = 0; q < 8; ++q) {
                    float4 xv = *(const float4*)&xk[4 * q];
                    acc0[4*q+0] = fmaf(a, xv.x, acc0[4*q+0]);
                    acc0[4*q+1] = fmaf(a, xv.y, acc0[4*q+1]);
                    acc0[4*q+2] = fmaf(a, xv.z, acc0[4*q+2]);
                    acc0[4*q+3] = fmaf(a, xv.w, acc0[4*q+3]);
                    acc1[4*q+0] = fmaf(b, xv.x, acc1[4*q+0]);
                    acc1[4*q+1] = fmaf(b, xv.y, acc1[4*q+1]);
                    acc1[4*q+2] = fmaf(b, xv.z, acc1[4*q+2]);
                    acc1[4*q+3] = fmaf(b, xv.w, acc1[4*q+3]);
                }
            }
        }

        // between phase 1 (X1) and phase 2 (X2): acc /= clip(rcnt,1)
        if (TWO && tile == nt1 - 1) {
            #pragma unroll
            for (int r = 0; r < 32; ++r) {
                int row = rowbase + (w << 5) + r;
                float c = (row < N) ? rcnt[row] : 1.f;
                c = c > 1.f ? c : 1.f;
                float inv = 1.f / c;
                acc0[r] *= inv; acc1[r] *= inv;
            }
        }

        __syncthreads();
        if (hasNext) {
            #pragma unroll
            for (int it = 0; it < 8; ++it) {
                int srow = ((it << 6) + (t >> 2)) & 127;
                int skq = (t & 3) + ((it >> 1) << 2);
                float* d = &xs[(4 * skq) * 132 + srow];
                d[0] = pf[it].x; d[132] = pf[it].y; d[264] = pf[it].z; d[396] = pf[it].w;
            }
        }
        __syncthreads();
    }

    float b0 = BIAS ? bias[lane] : 0.f;
    float b1 = BIAS ? bias[lane + 64] : 0.f;
    float wl0 = SCAL ? wlcol[lane] : 0.f;
    float wl1 = SCAL ? wlcol[lane + 64] : 0.f;
    #pragma unroll
    for (int r = 0; r < 32; ++r) {
        int row = rowbase + (w << 5) + r;
        if (row < N) {
            float v0 = acc0[r] + b0;
            float v1 = acc1[r] + b1;
            if (SCAL) {
                float c = cntS[row]; c = c > 1.f ? c : 1.f;
                float m = aggS[row] / c;
                v0 = fmaf(m, wl0, v0);
                v1 = fmaf(m, wl1, v1);
            }
            if (RELU) { v0 = fmaxf(v0, 0.f); v1 = fmaxf(v1, 0.f); }
            out[(size_t)row * 128 + lane] = v0;
            out[(size_t)row * 128 + lane + 64] = v1;
        }
    }
}

// ---------------- decoder over CSR ----------------
__global__ __launch_bounds__(256)
void k_decoder_csr(const int* __restrict__ off, const int* __restrict__ deg,
                   const int* __restrict__ srcs, const int* __restrict__ eidx,
                   const float* __restrict__ u, const float* __restrict__ v,
                   const float* __restrict__ wd2, const float* __restrict__ bd2,
                   float* __restrict__ out) {
    int node = (blockIdx.x * blockDim.x + threadIdx.x) >> 6;
    if (node >= NC) return;
    int lane = threadIdx.x & 63;
    int g = lane >> 3, s = lane & 7;

    const float4* wp = (const float4*)&wd2[s * 16];
    float4 w0 = wp[0], w1 = wp[1], w2 = wp[2], w3 = wp[3];
    float bb = bd2[0];

    const float4* vp = (const float4*)&v[(size_t)node * 128 + s * 16];
    float4 v0 = vp[0], v1 = vp[1], v2 = vp[2], v3 = vp[3];

    int b = off[node], d = deg[node];
    for (int jb = 0; jb < d; jb += 8) {
        int j = jb + g;
        float p = 0.f;
        int eid = 0;
        if (j < d) {
            int src = srcs[b + j];
            eid = eidx[b + j];
            const float4* up = (const float4*)&u[(size_t)src * 128 + s * 16];
            float4 u0 = up[0], u1 = up[1], u2 = up[2], u3 = up[3];
            p  = w0.x * fmaxf(u0.x + v0.x, 0.f) + w0.y * fmaxf(u0.y + v0.y, 0.f)
               + w0.z * fmaxf(u0.z + v0.z, 0.f) + w0.w * fmaxf(u0.w + v0.w, 0.f);
            p += w1.x * fmaxf(u1.x + v1.x, 0.f) + w1.y * fmaxf(u1.y + v1.y, 0.f)
               + w1.z * fmaxf(u1.z + v1.z, 0.f) + w1.w * fmaxf(u1.w + v1.w, 0.f);
            p += w2.x * fmaxf(u2.x + v2.x, 0.f) + w2.y * fmaxf(u2.y + v2.y, 0.f)
               + w2.z * fmaxf(u2.z + v2.z, 0.f) + w2.w * fmaxf(u2.w + v2.w, 0.f);
            p += w3.x * fmaxf(u3.x + v3.x, 0.f) + w3.y * fmaxf(u3.y + v3.y, 0.f)
               + w3.z * fmaxf(u3.z + v3.z, 0.f) + w3.w * fmaxf(u3.w + v3.w, 0.f);
        }
        p += __shfl_xor(p, 1);
        p += __shfl_xor(p, 2);
        p += __shfl_xor(p, 4);
        if (j < d && s == 0) out[eid] = p + bb;
    }
}

extern "C" void kernel_launch(void* const* d_in, const int* in_sizes, int n_in,
                              void* d_out, int out_size, void* d_ws, size_t ws_size,
                              hipStream_t stream) {
    const float* article_x = (const float*)d_in[0];
    const float* cx     = (const float*)d_in[1];
    const int*   e_wb   = (const int*)d_in[2];
    const int*   e_mb   = (const int*)d_in[3];
    const int*   e_cc   = (const int*)d_in[4];
    const float* W_lin1 = (const float*)d_in[5];
    const float* b_lin1 = (const float*)d_in[6];
    const float* Wl1    = (const float*)d_in[7];
    const float* bl1    = (const float*)d_in[8];
    const float* Wr1    = (const float*)d_in[9];
    const float* Wl2    = (const float*)d_in[10];
    const float* bl2    = (const float*)d_in[11];
    const float* Wr2    = (const float*)d_in[12];
    const float* Wl3    = (const float*)d_in[13];
    const float* bl3    = (const float*)d_in[14];
    const float* Wr3    = (const float*)d_in[15];
    const float* W_lin2 = (const float*)d_in[16];
    const float* b_lin2 = (const float*)d_in[17];
    const float* Wd1    = (const float*)d_in[18];
    const float* bd1    = (const float*)d_in[19];
    const float* Wd2    = (const float*)d_in[20];
    const float* bd2    = (const float*)d_in[21];
    float* out = (float*)d_out;

    const int E1 = in_sizes[2] / 2;
    const int E2 = in_sizes[3] / 2;
    const int E3 = in_sizes[4] / 2;

    float* ws = (float*)d_ws;
    size_t o = 0;
    float* art   = ws;      o += 1024;
    float* agg1  = ws + o;  o += NC;
    float* cnt1  = ws + o;  o += NC;
    float* agg2  = ws + o;  o += NC;
    float* cnt2  = ws + o;  o += NC;
    float* cnt3f = ws + o;  o += NC;
    float* B1 = ws + o; o += (size_t)NC * 128;
    float* B2 = ws + o; o += (size_t)NC * 128;
    int* deg    = (int*)(ws + o); o += NC;
    int* pre    = (int*)(ws + o); o += NC;
    int* off    = (int*)(ws + o); o += NC;
    int* cursor = (int*)(ws + o); o += NC;
    int* blksum = (int*)(ws + o); o += 256;
    int* srcs   = (int*)(ws + o); o += 800000;
    int* eidx   = (int*)(ws + o); o += 800000;

    hipMemsetAsync(agg1, 0, 4 * NC * sizeof(float), stream);   // agg1,cnt1,agg2,cnt2
    hipMemsetAsync(deg, 0, NC * sizeof(int), stream);

    k_art<<<256, 256, 0, stream>>>(article_x, W_lin1, b_lin1, art);

    k_edge_scalar<<<512, 256, 0, stream>>>(e_wb, E1, art, agg1, cnt1);
    k_edge_scalar<<<512, 256, 0, stream>>>(e_mb, E2, art, agg2, cnt2);

    // CSR build for e_cc
    const int NB = (NC + 1023) / 1024;  // 98
    k_hist<<<512, 256, 0, stream>>>(e_cc, E3, deg);
    k_scan1<<<NB, 256, 0, stream>>>(deg, pre, blksum);
    k_scan2<<<1, 256, 0, stream>>>(blksum, NB);
    k_scan3<<<(NC + 255) / 256, 256, 0, stream>>>(pre, blksum, deg, off, cursor, cnt3f);
    k_csr_scatter<<<512, 256, 0, stream>>>(e_cc, E3, cursor, srcs, eidx);

    const int GB2 = (NC + 127) / 128;      // 782 blocks
    const int GW = (NC * 64 + 255) / 256;  // 1 wave per node

    // h1 = relu(cx @ Wr1.T + bl1 + mean1*Wl1)                  -> B1
    k_gemm2<false, true, true, true><<<GB2, 256, 0, stream>>>(
        cx, 256, Wr1, 256, nullptr, 0, nullptr, 0,
        bl1, agg1, cnt1, Wl1, nullptr, B1, NC);
    // h2 = relu(h1 @ Wr2.T + bl2 + mean2*Wl2)                  -> B1 (in place)
    k_gemm2<false, true, true, true><<<GB2, 256, 0, stream>>>(
        B1, 128, Wr2, 128, nullptr, 0, nullptr, 0,
        bl2, agg2, cnt2, Wl2, nullptr, B1, NC);
    // agg3 = CSR gather-sum of h2                              -> B2
    k_csr_agg<<<GW, 256, 0, stream>>>(off, deg, srcs, B1, B2);
    // h3 = relu((agg3 @ Wl3.T)/cnt3 + bl3 + cx @ Wr3.T)        -> B1 (fused two-input)
    k_gemm2<true, true, false, true><<<GB2, 256, 0, stream>>>(
        B2, 128, Wl3, 128, cx, 256, Wr3, 256,
        bl3, nullptr, nullptr, nullptr, cnt3f, B1, NC);
    // z = h3 @ W_lin2.T + b_lin2                               -> B1 (in place)
    k_gemm2<false, false, false, true><<<GB2, 256, 0, stream>>>(
        B1, 128, W_lin2, 128, nullptr, 0, nullptr, 0,
        b_lin2, nullptr, nullptr, nullptr, nullptr, B1, NC);
    // v = z @ Wd1[:,128:].T                                    -> B2
    k_gemm2<false, false, false, false><<<GB2, 256, 0, stream>>>(
        B1, 128, Wd1 + 128, 256, nullptr, 0, nullptr, 0,
        nullptr, nullptr, nullptr, nullptr, nullptr, B2, NC);
    // u = z @ Wd1[:,:128].T + bd1                              -> B1 (in place)
    k_gemm2<false, false, false, true><<<GB2, 256, 0, stream>>>(
        B1, 128, Wd1, 256, nullptr, 0, nullptr, 0,
        bd1, nullptr, nullptr, nullptr, nullptr, B1, NC);

    k_decoder_csr<<<GW, 256, 0, stream>>>(off, deg, srcs, eidx, B1, B2, Wd2, bd2, out);
}

// Round 5
// 548.067 us; speedup vs baseline: 1.9680x; 1.9680x over previous
//
#include <hip/hip_runtime.h>

#define NC 100000
#define NA 1024
#define FA 4096

typedef _Float16 half8 __attribute__((ext_vector_type(8)));
typedef _Float16 half4v __attribute__((ext_vector_type(4)));
typedef _Float16 half2v __attribute__((ext_vector_type(2)));
typedef float floatx4 __attribute__((ext_vector_type(4)));

// ---------------- fp32 -> fp16 convert (vector x4) ----------------
__global__ void k_cvt4(const float* __restrict__ in, _Float16* __restrict__ out, int n4) {
    int i = blockIdx.x * blockDim.x + threadIdx.x;
    if (i < n4) {
        float4 v = ((const float4*)in)[i];
        half4v h = {(_Float16)v.x, (_Float16)v.y, (_Float16)v.z, (_Float16)v.w};
        ((half4v*)out)[i] = h;
    }
}

// ---------------- art[i] = article_x . W_lin1[i] + b_lin1[i] ----------------
__global__ void k_art(const float* __restrict__ ax, const float* __restrict__ W,
                      const float* __restrict__ b, float* __restrict__ art) {
    int wave = (blockIdx.x * blockDim.x + threadIdx.x) >> 6;
    int lane = threadIdx.x & 63;
    if (wave >= NA) return;
    const float* wr = W + (size_t)wave * FA;
    float s = 0.f;
    #pragma unroll
    for (int i = 0; i < FA; i += 256) {
        float4 a  = *(const float4*)&ax[i + 4 * lane];
        float4 wv = *(const float4*)&wr[i + 4 * lane];
        s += a.x * wv.x + a.y * wv.y + a.z * wv.z + a.w * wv.w;
    }
    for (int off = 32; off; off >>= 1) s += __shfl_down(s, off);
    if (lane == 0) art[wave] = s + b[wave];
}

// ---------------- scalar scatter: agg[dst] += art[src]; cnt[dst] += 1 ----------------
__global__ void k_edge_scalar(const int* __restrict__ ei, int E,
                              const float* __restrict__ art,
                              float* __restrict__ agg, float* __restrict__ cnt) {
    int t = blockIdx.x * blockDim.x + threadIdx.x;
    int stride = gridDim.x * blockDim.x;
    for (int e = t; e < E; e += stride) {
        int s = ei[e], d = ei[E + e];
        atomicAdd(&agg[d], art[s]);
        atomicAdd(&cnt[d], 1.0f);
    }
}

// ---------------- CSR build: histogram ----------------
__global__ void k_hist(const int* __restrict__ ei, int E, int* __restrict__ deg) {
    int t = blockIdx.x * blockDim.x + threadIdx.x;
    int stride = gridDim.x * blockDim.x;
    for (int e = t; e < E; e += stride) atomicAdd(&deg[ei[E + e]], 1);
}

// ---------------- CSR build: scan stage 1 ----------------
__global__ void k_scan1(const int* __restrict__ deg, int* __restrict__ pre,
                        int* __restrict__ blksum) {
    __shared__ int ts[256];
    int base = blockIdx.x * 1024 + threadIdx.x * 4;
    int v0 = 0, v1 = 0, v2 = 0, v3 = 0;
    if (base + 0 < NC) v0 = deg[base + 0];
    if (base + 1 < NC) v1 = deg[base + 1];
    if (base + 2 < NC) v2 = deg[base + 2];
    if (base + 3 < NC) v3 = deg[base + 3];
    int tsum = v0 + v1 + v2 + v3;
    ts[threadIdx.x] = tsum;
    __syncthreads();
    for (int off = 1; off < 256; off <<= 1) {
        int y = (threadIdx.x >= off) ? ts[threadIdx.x - off] : 0;
        __syncthreads();
        ts[threadIdx.x] += y;
        __syncthreads();
    }
    int excl = ts[threadIdx.x] - tsum;
    if (base + 0 < NC) pre[base + 0] = excl;
    if (base + 1 < NC) pre[base + 1] = excl + v0;
    if (base + 2 < NC) pre[base + 2] = excl + v0 + v1;
    if (base + 3 < NC) pre[base + 3] = excl + v0 + v1 + v2;
    if (threadIdx.x == 255) blksum[blockIdx.x] = ts[255];
}

// ---------------- CSR build: scan stage 2 ----------------
__global__ void k_scan2(int* __restrict__ blksum, int NB) {
    __shared__ int ts[256];
    int v = (threadIdx.x < NB) ? blksum[threadIdx.x] : 0;
    ts[threadIdx.x] = v;
    __syncthreads();
    for (int off = 1; off < 256; off <<= 1) {
        int y = (threadIdx.x >= off) ? ts[threadIdx.x - off] : 0;
        __syncthreads();
        ts[threadIdx.x] += y;
        __syncthreads();
    }
    if (threadIdx.x < NB) blksum[threadIdx.x] = ts[threadIdx.x] - v;  // exclusive
}

// ---------------- CSR build: scan stage 3 ----------------
__global__ void k_scan3(const int* __restrict__ pre, const int* __restrict__ blksum,
                        const int* __restrict__ deg, int* __restrict__ off,
                        int* __restrict__ cursor, float* __restrict__ cntf) {
    int i = blockIdx.x * blockDim.x + threadIdx.x;
    if (i < NC) {
        int o = pre[i] + blksum[i >> 10];
        off[i] = o;
        cursor[i] = o;
        cntf[i] = (float)deg[i];
    }
}

// ---------------- CSR build: scatter (src, edge-id) ----------------
__global__ void k_csr_scatter(const int* __restrict__ ei, int E,
                              int* __restrict__ cursor, int* __restrict__ srcs,
                              int* __restrict__ eidx) {
    int t = blockIdx.x * blockDim.x + threadIdx.x;
    int stride = gridDim.x * blockDim.x;
    for (int e = t; e < E; e += stride) {
        int s = ei[e], d = ei[E + e];
        int p = atomicAdd(&cursor[d], 1);
        srcs[p] = s;
        eidx[p] = e;
    }
}

// ---------------- CSR aggregate (fp16 in, fp32 sum, fp16 out) ----------------
__global__ __launch_bounds__(256)
void k_csr_agg_h(const int* __restrict__ off, const int* __restrict__ deg,
                 const int* __restrict__ srcs, const _Float16* __restrict__ h,
                 _Float16* __restrict__ agg) {
    int node = (blockIdx.x * blockDim.x + threadIdx.x) >> 6;
    int lane = threadIdx.x & 63;
    if (node >= NC) return;
    int b = off[node], d = deg[node];
    float sx = 0.f, sy = 0.f;
    for (int j = 0; j < d; ++j) {
        int src = srcs[b + j];
        half2v m = *(const half2v*)&h[(size_t)src * 128 + 2 * lane];
        sx += (float)m[0]; sy += (float)m[1];
    }
    half2v r = {(_Float16)sx, (_Float16)sy};
    *(half2v*)&agg[(size_t)node * 128 + 2 * lane] = r;
}

// ---------------- MFMA fp16 GEMM: out[i][f] = act(X1.W1 (/cnt) + X2.W2 + ...) ----------------
// W layout: [128 out][K] row-major fp16, row stride lda. X fp16 row-major [N][K].
// Block 256 = 4 waves, BM=128 BN=128 BK=32. Wave w: rows [32w,32w+32) via 2 A-frags;
// 8 B col-frags. LDS A/B tiles [128][40] halves; threads<128 stage A, >=128 stage B.
template<bool TWO, bool RELU, bool SCAL, bool BIAS>
__global__ __launch_bounds__(256)
void k_gemm_h(const _Float16* __restrict__ X1, int K1,
              const _Float16* __restrict__ W1, int lda1,
              const _Float16* __restrict__ X2, int K2,
              const _Float16* __restrict__ W2, int lda2,
              const float* __restrict__ bias,
              const float* __restrict__ aggS, const float* __restrict__ cntS,
              const float* __restrict__ wlcol, const float* __restrict__ rcnt,
              _Float16* __restrict__ out, int N)
{
    __shared__ _Float16 Ah[128 * 40];
    __shared__ _Float16 Bh[128 * 40];
    const int t = threadIdx.x, lane = t & 63, w = t >> 6;
    const int rowbase = blockIdx.x * 128;
    const int nt1 = K1 >> 5;
    const int nt = TWO ? nt1 + (K2 >> 5) : nt1;

    floatx4 zero4 = {0.f, 0.f, 0.f, 0.f};
    floatx4 acc[2][8];
    #pragma unroll
    for (int i = 0; i < 2; ++i)
        #pragma unroll
        for (int cf = 0; cf < 8; ++cf) acc[i][cf] = zero4;

    const bool isA = (t < 128);
    const int rr = isA ? t : t - 128;   // A: row-in-tile; B: out-col

    float4 p0, p1, p2, p3;
    {
        bool ok = true;
        const _Float16* base;
        if (isA) { int row = rowbase + rr; ok = row < N; base = ok ? &X1[(size_t)row * K1] : Ah; }
        else base = &W1[(size_t)rr * lda1];
        const float4* s4 = (const float4*)base;
        float4 zf = make_float4(0.f, 0.f, 0.f, 0.f);
        p0 = ok ? s4[0] : zf; p1 = ok ? s4[1] : zf;
        p2 = ok ? s4[2] : zf; p3 = ok ? s4[3] : zf;
    }

    const int fr = lane & 15;
    const int kq = (lane >> 4) << 3;   // halves offset in k

    for (int tile = 0; tile < nt; ++tile) {
        float4* dst = (float4*)(isA ? &Ah[rr * 40] : &Bh[rr * 40]);
        dst[0] = p0; dst[1] = p1; dst[2] = p2; dst[3] = p3;
        __syncthreads();

        int tn = tile + 1;
        if (tn < nt) {
            bool ok = true;
            const _Float16* base;
            if (!TWO || tn < nt1) {
                int ko = tn << 5;
                if (isA) { int row = rowbase + rr; ok = row < N; base = ok ? &X1[(size_t)row * K1 + ko] : Ah; }
                else base = &W1[(size_t)rr * lda1 + ko];
            } else {
                int ko = (tn - nt1) << 5;
                if (isA) { int row = rowbase + rr; ok = row < N; base = ok ? &X2[(size_t)row * K2 + ko] : Ah; }
                else base = &W2[(size_t)rr * lda2 + ko];
            }
            const float4* s4 = (const float4*)base;
            float4 zf = make_float4(0.f, 0.f, 0.f, 0.f);
            p0 = ok ? s4[0] : zf; p1 = ok ? s4[1] : zf;
            p2 = ok ? s4[2] : zf; p3 = ok ? s4[3] : zf;
        }

        half8 af0 = *(const half8*)&Ah[(w * 32 + fr) * 40 + kq];
        half8 af1 = *(const half8*)&Ah[(w * 32 + 16 + fr) * 40 + kq];
        #pragma unroll
        for (int cf = 0; cf < 8; ++cf) {
            half8 bf = *(const half8*)&Bh[(cf * 16 + fr) * 40 + kq];
            acc[0][cf] = __builtin_amdgcn_mfma_f32_16x16x32_f16(af0, bf, acc[0][cf], 0, 0, 0);
            acc[1][cf] = __builtin_amdgcn_mfma_f32_16x16x32_f16(af1, bf, acc[1][cf], 0, 0, 0);
        }

        if (TWO && tile == nt1 - 1) {
            #pragma unroll
            for (int i = 0; i < 2; ++i)
                #pragma unroll
                for (int j = 0; j < 4; ++j) {
                    int row = rowbase + w * 32 + i * 16 + ((lane >> 4) << 2) + j;
                    float c = (row < N) ? rcnt[row] : 1.f;
                    c = c > 1.f ? c : 1.f;
                    float inv = 1.f / c;
                    #pragma unroll
                    for (int cf = 0; cf < 8; ++cf) acc[i][cf][j] *= inv;
                }
        }
        __syncthreads();
    }

    #pragma unroll
    for (int i = 0; i < 2; ++i) {
        #pragma unroll
        for (int j = 0; j < 4; ++j) {
            int row = rowbase + w * 32 + i * 16 + ((lane >> 4) << 2) + j;
            if (row < N) {
                float m = 0.f;
                if (SCAL) { float c = cntS[row]; c = c > 1.f ? c : 1.f; m = aggS[row] / c; }
                #pragma unroll
                for (int cf = 0; cf < 8; ++cf) {
                    int col = cf * 16 + fr;
                    float v = acc[i][cf][j];
                    if (BIAS) v += bias[col];
                    if (SCAL) v = fmaf(m, wlcol[col], v);
                    if (RELU) v = fmaxf(v, 0.f);
                    out[(size_t)row * 128 + col] = (_Float16)v;
                }
            }
        }
    }
}

// ---------------- decoder over CSR (fp16 u,v) ----------------
__global__ __launch_bounds__(256)
void k_decoder_h(const int* __restrict__ off, const int* __restrict__ deg,
                 const int* __restrict__ srcs, const int* __restrict__ eidx,
                 const _Float16* __restrict__ u, const _Float16* __restrict__ v,
                 const float* __restrict__ wd2, const float* __restrict__ bd2,
                 float* __restrict__ out) {
    int node = (blockIdx.x * blockDim.x + threadIdx.x) >> 6;
    if (node >= NC) return;
    int lane = threadIdx.x & 63;
    int g = lane >> 3, s = lane & 7;

    float wf[16], vf[16];
    #pragma unroll
    for (int q = 0; q < 16; ++q) wf[q] = wd2[s * 16 + q];
    {
        half8 va = *(const half8*)&v[(size_t)node * 128 + s * 16];
        half8 vb = *(const half8*)&v[(size_t)node * 128 + s * 16 + 8];
        #pragma unroll
        for (int q = 0; q < 8; ++q) { vf[q] = (float)va[q]; vf[8 + q] = (float)vb[q]; }
    }
    float bb = bd2[0];

    int b = off[node], d = deg[node];
    for (int jb = 0; jb < d; jb += 8) {
        int j = jb + g;
        float p = 0.f;
        int eid = 0;
        if (j < d) {
            int src = srcs[b + j];
            eid = eidx[b + j];
            half8 ua = *(const half8*)&u[(size_t)src * 128 + s * 16];
            half8 ub = *(const half8*)&u[(size_t)src * 128 + s * 16 + 8];
            #pragma unroll
            for (int q = 0; q < 8; ++q) {
                p = fmaf(wf[q],     fmaxf((float)ua[q] + vf[q],     0.f), p);
                p = fmaf(wf[8 + q], fmaxf((float)ub[q] + vf[8 + q], 0.f), p);
            }
        }
        p += __shfl_xor(p, 1);
        p += __shfl_xor(p, 2);
        p += __shfl_xor(p, 4);
        if (j < d && s == 0) out[eid] = p + bb;
    }
}

extern "C" void kernel_launch(void* const* d_in, const int* in_sizes, int n_in,
                              void* d_out, int out_size, void* d_ws, size_t ws_size,
                              hipStream_t stream) {
    const float* article_x = (const float*)d_in[0];
    const float* cx     = (const float*)d_in[1];
    const int*   e_wb   = (const int*)d_in[2];
    const int*   e_mb   = (const int*)d_in[3];
    const int*   e_cc   = (const int*)d_in[4];
    const float* W_lin1 = (const float*)d_in[5];
    const float* b_lin1 = (const float*)d_in[6];
    const float* Wl1    = (const float*)d_in[7];
    const float* bl1    = (const float*)d_in[8];
    const float* Wr1    = (const float*)d_in[9];
    const float* Wl2    = (const float*)d_in[10];
    const float* bl2    = (const float*)d_in[11];
    const float* Wr2    = (const float*)d_in[12];
    const float* Wl3    = (const float*)d_in[13];
    const float* bl3    = (const float*)d_in[14];
    const float* Wr3    = (const float*)d_in[15];
    const float* W_lin2 = (const float*)d_in[16];
    const float* b_lin2 = (const float*)d_in[17];
    const float* Wd1    = (const float*)d_in[18];
    const float* bd1    = (const float*)d_in[19];
    const float* Wd2    = (const float*)d_in[20];
    const float* bd2    = (const float*)d_in[21];
    float* out = (float*)d_out;

    const int E1 = in_sizes[2] / 2;
    const int E2 = in_sizes[3] / 2;
    const int E3 = in_sizes[4] / 2;

    float* ws = (float*)d_ws;
    size_t o = 0;
    float* art   = ws;      o += 1024;
    float* agg1  = ws + o;  o += NC;
    float* cnt1  = ws + o;  o += NC;
    float* agg2  = ws + o;  o += NC;
    float* cnt2  = ws + o;  o += NC;
    float* cnt3f = ws + o;  o += NC;
    int* deg    = (int*)(ws + o); o += NC;
    int* pre    = (int*)(ws + o); o += NC;
    int* off    = (int*)(ws + o); o += NC;
    int* cursor = (int*)(ws + o); o += NC;
    int* blksum = (int*)(ws + o); o += 256;
    int* srcs   = (int*)(ws + o); o += 800000;
    int* eidx   = (int*)(ws + o); o += 800000;
    // fp16 arena
    _Float16* hws = (_Float16*)(ws + o);
    size_t ho = 0;
    _Float16* cxh    = hws + ho; ho += (size_t)NC * 256;
    _Float16* B1h    = hws + ho; ho += (size_t)NC * 128;
    _Float16* B2h    = hws + ho; ho += (size_t)NC * 128;
    _Float16* Wr1h   = hws + ho; ho += 128 * 256;
    _Float16* Wr2h   = hws + ho; ho += 128 * 128;
    _Float16* Wl3h   = hws + ho; ho += 128 * 128;
    _Float16* Wr3h   = hws + ho; ho += 128 * 256;
    _Float16* Wlin2h = hws + ho; ho += 128 * 128;
    _Float16* Wd1h   = hws + ho; ho += 128 * 256;

    hipMemsetAsync(agg1, 0, 4 * NC * sizeof(float), stream);   // agg1,cnt1,agg2,cnt2
    hipMemsetAsync(deg, 0, NC * sizeof(int), stream);

    // conversions
    k_cvt4<<<(NC * 256 / 4 + 255) / 256, 256, 0, stream>>>(cx, cxh, NC * 256 / 4);
    k_cvt4<<<32, 256, 0, stream>>>(Wr1, Wr1h, 128 * 256 / 4);
    k_cvt4<<<16, 256, 0, stream>>>(Wr2, Wr2h, 128 * 128 / 4);
    k_cvt4<<<16, 256, 0, stream>>>(Wl3, Wl3h, 128 * 128 / 4);
    k_cvt4<<<32, 256, 0, stream>>>(Wr3, Wr3h, 128 * 256 / 4);
    k_cvt4<<<16, 256, 0, stream>>>(W_lin2, Wlin2h, 128 * 128 / 4);
    k_cvt4<<<32, 256, 0, stream>>>(Wd1, Wd1h, 128 * 256 / 4);

    k_art<<<256, 256, 0, stream>>>(article_x, W_lin1, b_lin1, art);

    k_edge_scalar<<<512, 256, 0, stream>>>(e_wb, E1, art, agg1, cnt1);
    k_edge_scalar<<<512, 256, 0, stream>>>(e_mb, E2, art, agg2, cnt2);

    // CSR build for e_cc
    const int NB = (NC + 1023) / 1024;  // 98
    k_hist<<<512, 256, 0, stream>>>(e_cc, E3, deg);
    k_scan1<<<NB, 256, 0, stream>>>(deg, pre, blksum);
    k_scan2<<<1, 256, 0, stream>>>(blksum, NB);
    k_scan3<<<(NC + 255) / 256, 256, 0, stream>>>(pre, blksum, deg, off, cursor, cnt3f);
    k_csr_scatter<<<512, 256, 0, stream>>>(e_cc, E3, cursor, srcs, eidx);

    const int GB = (NC + 127) / 128;       // 782 blocks
    const int GW = (NC * 64 + 255) / 256;  // 1 wave per node

    // h1 = relu(cxh @ Wr1.T + bl1 + mean1*Wl1)                 -> B1h
    k_gemm_h<false, true, true, true><<<GB, 256, 0, stream>>>(
        cxh, 256, Wr1h, 256, nullptr, 0, nullptr, 0,
        bl1, agg1, cnt1, Wl1, nullptr, B1h, NC);
    // h2 = relu(h1 @ Wr2.T + bl2 + mean2*Wl2)                  -> B1h (in place)
    k_gemm_h<false, true, true, true><<<GB, 256, 0, stream>>>(
        B1h, 128, Wr2h, 128, nullptr, 0, nullptr, 0,
        bl2, agg2, cnt2, Wl2, nullptr, B1h, NC);
    // agg3 = CSR gather-sum of h2                              -> B2h
    k_csr_agg_h<<<GW, 256, 0, stream>>>(off, deg, srcs, B1h, B2h);
    // h3 = relu((agg3 @ Wl3.T)/cnt3 + bl3 + cxh @ Wr3.T)       -> B1h
    k_gemm_h<true, true, false, true><<<GB, 256, 0, stream>>>(
        B2h, 128, Wl3h, 128, cxh, 256, Wr3h, 256,
        bl3, nullptr, nullptr, nullptr, cnt3f, B1h, NC);
    // z = h3 @ W_lin2.T + b_lin2                               -> B1h (in place)
    k_gemm_h<false, false, false, true><<<GB, 256, 0, stream>>>(
        B1h, 128, Wlin2h, 128, nullptr, 0, nullptr, 0,
        b_lin2, nullptr, nullptr, nullptr, nullptr, B1h, NC);
    // v = z @ Wd1[:,128:].T                                    -> B2h
    k_gemm_h<false, false, false, false><<<GB, 256, 0, stream>>>(
        B1h, 128, Wd1h + 128, 256, nullptr, 0, nullptr, 0,
        nullptr, nullptr, nullptr, nullptr, nullptr, B2h, NC);
    // u = z @ Wd1[:,:128].T + bd1                              -> B1h (in place)
    k_gemm_h<false, false, false, true><<<GB, 256, 0, stream>>>(
        B1h, 128, Wd1h, 256, nullptr, 0, nullptr, 0,
        bd1, nullptr, nullptr, nullptr, nullptr, B1h, NC);

    k_decoder_h<<<GW, 256, 0, stream>>>(off, deg, srcs, eidx, B1h, B2h, Wd2, bd2, out);
}

// Round 6
// 511.861 us; speedup vs baseline: 2.1072x; 1.0707x over previous
//
#include <hip/hip_runtime.h>

#define NC 100000
#define NA 1024
#define FA 4096

typedef _Float16 half8 __attribute__((ext_vector_type(8)));
typedef _Float16 half4v __attribute__((ext_vector_type(4)));
typedef _Float16 half2v __attribute__((ext_vector_type(2)));
typedef float floatx4 __attribute__((ext_vector_type(4)));

// ---------------- fp32 -> fp16 convert (vector x4) ----------------
__global__ void k_cvt4(const float* __restrict__ in, _Float16* __restrict__ out, int n4) {
    int i = blockIdx.x * blockDim.x + threadIdx.x;
    if (i < n4) {
        float4 v = ((const float4*)in)[i];
        half4v h = {(_Float16)v.x, (_Float16)v.y, (_Float16)v.z, (_Float16)v.w};
        ((half4v*)out)[i] = h;
    }
}

// ---------------- weight folding: Wu = Wd1[:, :128] @ Wlin2, Wv = Wd1[:,128:] @ Wlin2 ----------------
__global__ void k_wcomb(const float* __restrict__ Wd1, const float* __restrict__ Wlin2,
                        _Float16* __restrict__ Wuh, _Float16* __restrict__ Wvh) {
    int i = blockIdx.x;      // 128 blocks = output row
    int j = threadIdx.x;     // 128 threads = output col (k of folded weight)
    float au = 0.f, av = 0.f;
    for (int m = 0; m < 128; ++m) {
        float wl = Wlin2[m * 128 + j];
        au = fmaf(Wd1[i * 256 + m], wl, au);
        av = fmaf(Wd1[i * 256 + 128 + m], wl, av);
    }
    Wuh[i * 128 + j] = (_Float16)au;
    Wvh[i * 128 + j] = (_Float16)av;
}

// ---------------- bias folding: bu = Wd1a@b2 + bd1, bv = Wd1b@b2 ----------------
__global__ void k_bcomb(const float* __restrict__ Wd1, const float* __restrict__ b2,
                        const float* __restrict__ bd1,
                        float* __restrict__ bu, float* __restrict__ bv) {
    int i = threadIdx.x;   // 128 threads
    float su = 0.f, sv = 0.f;
    for (int m = 0; m < 128; ++m) {
        float b = b2[m];
        su = fmaf(Wd1[i * 256 + m], b, su);
        sv = fmaf(Wd1[i * 256 + 128 + m], b, sv);
    }
    bu[i] = su + bd1[i];
    bv[i] = sv;
}

// ---------------- art[i] = article_x . W_lin1[i] + b_lin1[i] ----------------
__global__ void k_art(const float* __restrict__ ax, const float* __restrict__ W,
                      const float* __restrict__ b, float* __restrict__ art) {
    int wave = (blockIdx.x * blockDim.x + threadIdx.x) >> 6;
    int lane = threadIdx.x & 63;
    if (wave >= NA) return;
    const float* wr = W + (size_t)wave * FA;
    float s = 0.f;
    #pragma unroll
    for (int i = 0; i < FA; i += 256) {
        float4 a  = *(const float4*)&ax[i + 4 * lane];
        float4 wv = *(const float4*)&wr[i + 4 * lane];
        s += a.x * wv.x + a.y * wv.y + a.z * wv.z + a.w * wv.w;
    }
    for (int off = 32; off; off >>= 1) s += __shfl_down(s, off);
    if (lane == 0) art[wave] = s + b[wave];
}

// ---------------- scalar scatter: agg[dst] += art[src]; cnt[dst] += 1 ----------------
__global__ void k_edge_scalar(const int* __restrict__ ei, int E,
                              const float* __restrict__ art,
                              float* __restrict__ agg, float* __restrict__ cnt) {
    int t = blockIdx.x * blockDim.x + threadIdx.x;
    int stride = gridDim.x * blockDim.x;
    for (int e = t; e < E; e += stride) {
        int s = ei[e], d = ei[E + e];
        atomicAdd(&agg[d], art[s]);
        atomicAdd(&cnt[d], 1.0f);
    }
}

// ---------------- CSR build: histogram ----------------
__global__ void k_hist(const int* __restrict__ ei, int E, int* __restrict__ deg) {
    int t = blockIdx.x * blockDim.x + threadIdx.x;
    int stride = gridDim.x * blockDim.x;
    for (int e = t; e < E; e += stride) atomicAdd(&deg[ei[E + e]], 1);
}

// ---------------- CSR build: scan stage 1 ----------------
__global__ void k_scan1(const int* __restrict__ deg, int* __restrict__ pre,
                        int* __restrict__ blksum) {
    __shared__ int ts[256];
    int base = blockIdx.x * 1024 + threadIdx.x * 4;
    int v0 = 0, v1 = 0, v2 = 0, v3 = 0;
    if (base + 0 < NC) v0 = deg[base + 0];
    if (base + 1 < NC) v1 = deg[base + 1];
    if (base + 2 < NC) v2 = deg[base + 2];
    if (base + 3 < NC) v3 = deg[base + 3];
    int tsum = v0 + v1 + v2 + v3;
    ts[threadIdx.x] = tsum;
    __syncthreads();
    for (int off = 1; off < 256; off <<= 1) {
        int y = (threadIdx.x >= off) ? ts[threadIdx.x - off] : 0;
        __syncthreads();
        ts[threadIdx.x] += y;
        __syncthreads();
    }
    int excl = ts[threadIdx.x] - tsum;
    if (base + 0 < NC) pre[base + 0] = excl;
    if (base + 1 < NC) pre[base + 1] = excl + v0;
    if (base + 2 < NC) pre[base + 2] = excl + v0 + v1;
    if (base + 3 < NC) pre[base + 3] = excl + v0 + v1 + v2;
    if (threadIdx.x == 255) blksum[blockIdx.x] = ts[255];
}

// ---------------- CSR build: scan stage 2 ----------------
__global__ void k_scan2(int* __restrict__ blksum, int NB) {
    __shared__ int ts[256];
    int v = (threadIdx.x < NB) ? blksum[threadIdx.x] : 0;
    ts[threadIdx.x] = v;
    __syncthreads();
    for (int off = 1; off < 256; off <<= 1) {
        int y = (threadIdx.x >= off) ? ts[threadIdx.x - off] : 0;
        __syncthreads();
        ts[threadIdx.x] += y;
        __syncthreads();
    }
    if (threadIdx.x < NB) blksum[threadIdx.x] = ts[threadIdx.x] - v;  // exclusive
}

// ---------------- CSR build: scan stage 3 ----------------
__global__ void k_scan3(const int* __restrict__ pre, const int* __restrict__ blksum,
                        const int* __restrict__ deg, int* __restrict__ off,
                        int* __restrict__ cursor, float* __restrict__ cntf) {
    int i = blockIdx.x * blockDim.x + threadIdx.x;
    if (i < NC) {
        int o = pre[i] + blksum[i >> 10];
        off[i] = o;
        cursor[i] = o;
        cntf[i] = (float)deg[i];
    }
}

// ---------------- CSR build: scatter (src, edge-id) ----------------
__global__ void k_csr_scatter(const int* __restrict__ ei, int E,
                              int* __restrict__ cursor, int* __restrict__ srcs,
                              int* __restrict__ eidx) {
    int t = blockIdx.x * blockDim.x + threadIdx.x;
    int stride = gridDim.x * blockDim.x;
    for (int e = t; e < E; e += stride) {
        int s = ei[e], d = ei[E + e];
        int p = atomicAdd(&cursor[d], 1);
        srcs[p] = s;
        eidx[p] = e;
    }
}

// ---------------- CSR aggregate (fp16 in, fp32 sum, fp16 out) ----------------
// Prefetch bucket src indices via one lane-parallel load, distribute via shfl:
// removes the dependent srcs->gather chain, lets unrolled gathers pipeline.
__global__ __launch_bounds__(256)
void k_csr_agg_h(const int* __restrict__ off, const int* __restrict__ deg,
                 const int* __restrict__ srcs, const _Float16* __restrict__ h,
                 _Float16* __restrict__ agg) {
    int node = (blockIdx.x * blockDim.x + threadIdx.x) >> 6;
    int lane = threadIdx.x & 63;
    if (node >= NC) return;
    int b = off[node], d = deg[node];
    int dm = d < 64 ? d : 64;
    int sj = 0;
    if (lane < dm) sj = srcs[b + lane];
    float sx = 0.f, sy = 0.f;
    #pragma unroll 4
    for (int j = 0; j < dm; ++j) {
        int src = __shfl(sj, j);
        half2v m = *(const half2v*)&h[(size_t)src * 128 + 2 * lane];
        sx += (float)m[0]; sy += (float)m[1];
    }
    for (int j = 64; j < d; ++j) {
        int src = srcs[b + j];
        half2v m = *(const half2v*)&h[(size_t)src * 128 + 2 * lane];
        sx += (float)m[0]; sy += (float)m[1];
    }
    half2v r = {(_Float16)sx, (_Float16)sy};
    *(half2v*)&agg[(size_t)node * 128 + 2 * lane] = r;
}

// ---------------- MFMA fp16 GEMM: out[i][f] = act(X1.W1 (/cnt) + X2.W2 + ...) ----------------
template<bool TWO, bool RELU, bool SCAL, bool BIAS>
__global__ __launch_bounds__(256)
void k_gemm_h(const _Float16* __restrict__ X1, int K1,
              const _Float16* __restrict__ W1, int lda1,
              const _Float16* __restrict__ X2, int K2,
              const _Float16* __restrict__ W2, int lda2,
              const float* __restrict__ bias,
              const float* __restrict__ aggS, const float* __restrict__ cntS,
              const float* __restrict__ wlcol, const float* __restrict__ rcnt,
              _Float16* __restrict__ out, int N)
{
    __shared__ _Float16 Ah[128 * 40];
    __shared__ _Float16 Bh[128 * 40];
    const int t = threadIdx.x, lane = t & 63, w = t >> 6;
    const int rowbase = blockIdx.x * 128;
    const int nt1 = K1 >> 5;
    const int nt = TWO ? nt1 + (K2 >> 5) : nt1;

    floatx4 zero4 = {0.f, 0.f, 0.f, 0.f};
    floatx4 acc[2][8];
    #pragma unroll
    for (int i = 0; i < 2; ++i)
        #pragma unroll
        for (int cf = 0; cf < 8; ++cf) acc[i][cf] = zero4;

    const bool isA = (t < 128);
    const int rr = isA ? t : t - 128;   // A: row-in-tile; B: out-col

    float4 p0, p1, p2, p3;
    {
        bool ok = true;
        const _Float16* base;
        if (isA) { int row = rowbase + rr; ok = row < N; base = ok ? &X1[(size_t)row * K1] : Ah; }
        else base = &W1[(size_t)rr * lda1];
        const float4* s4 = (const float4*)base;
        float4 zf = make_float4(0.f, 0.f, 0.f, 0.f);
        p0 = ok ? s4[0] : zf; p1 = ok ? s4[1] : zf;
        p2 = ok ? s4[2] : zf; p3 = ok ? s4[3] : zf;
    }

    const int fr = lane & 15;
    const int kq = (lane >> 4) << 3;   // halves offset in k

    for (int tile = 0; tile < nt; ++tile) {
        float4* dst = (float4*)(isA ? &Ah[rr * 40] : &Bh[rr * 40]);
        dst[0] = p0; dst[1] = p1; dst[2] = p2; dst[3] = p3;
        __syncthreads();

        int tn = tile + 1;
        if (tn < nt) {
            bool ok = true;
            const _Float16* base;
            if (!TWO || tn < nt1) {
                int ko = tn << 5;
                if (isA) { int row = rowbase + rr; ok = row < N; base = ok ? &X1[(size_t)row * K1 + ko] : Ah; }
                else base = &W1[(size_t)rr * lda1 + ko];
            } else {
                int ko = (tn - nt1) << 5;
                if (isA) { int row = rowbase + rr; ok = row < N; base = ok ? &X2[(size_t)row * K2 + ko] : Ah; }
                else base = &W2[(size_t)rr * lda2 + ko];
            }
            const float4* s4 = (const float4*)base;
            float4 zf = make_float4(0.f, 0.f, 0.f, 0.f);
            p0 = ok ? s4[0] : zf; p1 = ok ? s4[1] : zf;
            p2 = ok ? s4[2] : zf; p3 = ok ? s4[3] : zf;
        }

        half8 af0 = *(const half8*)&Ah[(w * 32 + fr) * 40 + kq];
        half8 af1 = *(const half8*)&Ah[(w * 32 + 16 + fr) * 40 + kq];
        #pragma unroll
        for (int cf = 0; cf < 8; ++cf) {
            half8 bf = *(const half8*)&Bh[(cf * 16 + fr) * 40 + kq];
            acc[0][cf] = __builtin_amdgcn_mfma_f32_16x16x32_f16(af0, bf, acc[0][cf], 0, 0, 0);
            acc[1][cf] = __builtin_amdgcn_mfma_f32_16x16x32_f16(af1, bf, acc[1][cf], 0, 0, 0);
        }

        if (TWO && tile == nt1 - 1) {
            #pragma unroll
            for (int i = 0; i < 2; ++i)
                #pragma unroll
                for (int j = 0; j < 4; ++j) {
                    int row = rowbase + w * 32 + i * 16 + ((lane >> 4) << 2) + j;
                    float c = (row < N) ? rcnt[row] : 1.f;
                    c = c > 1.f ? c : 1.f;
                    float inv = 1.f / c;
                    #pragma unroll
                    for (int cf = 0; cf < 8; ++cf) acc[i][cf][j] *= inv;
                }
        }
        __syncthreads();
    }

    #pragma unroll
    for (int i = 0; i < 2; ++i) {
        #pragma unroll
        for (int j = 0; j < 4; ++j) {
            int row = rowbase + w * 32 + i * 16 + ((lane >> 4) << 2) + j;
            if (row < N) {
                float m = 0.f;
                if (SCAL) { float c = cntS[row]; c = c > 1.f ? c : 1.f; m = aggS[row] / c; }
                #pragma unroll
                for (int cf = 0; cf < 8; ++cf) {
                    int col = cf * 16 + fr;
                    float v = acc[i][cf][j];
                    if (BIAS) v += bias[col];
                    if (SCAL) v = fmaf(m, wlcol[col], v);
                    if (RELU) v = fmaxf(v, 0.f);
                    out[(size_t)row * 128 + col] = (_Float16)v;
                }
            }
        }
    }
}

// ---------------- decoder over CSR (fp16 u,v), prefetched src/eidx ----------------
__global__ __launch_bounds__(256)
void k_decoder_h(const int* __restrict__ off, const int* __restrict__ deg,
                 const int* __restrict__ srcs, const int* __restrict__ eidx,
                 const _Float16* __restrict__ u, const _Float16* __restrict__ v,
                 const float* __restrict__ wd2, const float* __restrict__ bd2,
                 float* __restrict__ out) {
    int node = (blockIdx.x * blockDim.x + threadIdx.x) >> 6;
    if (node >= NC) return;
    int lane = threadIdx.x & 63;
    int g = lane >> 3, s = lane & 7;

    float wf[16], vf[16];
    #pragma unroll
    for (int q = 0; q < 16; ++q) wf[q] = wd2[s * 16 + q];
    {
        half8 va = *(const half8*)&v[(size_t)node * 128 + s * 16];
        half8 vb = *(const half8*)&v[(size_t)node * 128 + s * 16 + 8];
        #pragma unroll
        for (int q = 0; q < 8; ++q) { vf[q] = (float)va[q]; vf[8 + q] = (float)vb[q]; }
    }
    float bb = bd2[0];

    int b = off[node], d = deg[node];
    int dm = d < 64 ? d : 64;
    int sj = 0, ej = 0;
    if (lane < dm) { sj = srcs[b + lane]; ej = eidx[b + lane]; }

    for (int jb = 0; jb < d; jb += 8) {
        int j = jb + g;
        float p = 0.f;
        int eid = 0;
        bool act = j < d;
        int src = 0;
        if (jb < 64) {             // uniform branch (jb multiple of 8)
            src = __shfl(sj, j);
            eid = __shfl(ej, j);
        } else if (act) {
            src = srcs[b + j];
            eid = eidx[b + j];
        }
        if (act) {
            half8 ua = *(const half8*)&u[(size_t)src * 128 + s * 16];
            half8 ub = *(const half8*)&u[(size_t)src * 128 + s * 16 + 8];
            #pragma unroll
            for (int q = 0; q < 8; ++q) {
                p = fmaf(wf[q],     fmaxf((float)ua[q] + vf[q],     0.f), p);
                p = fmaf(wf[8 + q], fmaxf((float)ub[q] + vf[8 + q], 0.f), p);
            }
        }
        p += __shfl_xor(p, 1);
        p += __shfl_xor(p, 2);
        p += __shfl_xor(p, 4);
        if (act && s == 0) out[eid] = p + bb;
    }
}

extern "C" void kernel_launch(void* const* d_in, const int* in_sizes, int n_in,
                              void* d_out, int out_size, void* d_ws, size_t ws_size,
                              hipStream_t stream) {
    const float* article_x = (const float*)d_in[0];
    const float* cx     = (const float*)d_in[1];
    const int*   e_wb   = (const int*)d_in[2];
    const int*   e_mb   = (const int*)d_in[3];
    const int*   e_cc   = (const int*)d_in[4];
    const float* W_lin1 = (const float*)d_in[5];
    const float* b_lin1 = (const float*)d_in[6];
    const float* Wl1    = (const float*)d_in[7];
    const float* bl1    = (const float*)d_in[8];
    const float* Wr1    = (const float*)d_in[9];
    const float* Wl2    = (const float*)d_in[10];
    const float* bl2    = (const float*)d_in[11];
    const float* Wr2    = (const float*)d_in[12];
    const float* Wl3    = (const float*)d_in[13];
    const float* bl3    = (const float*)d_in[14];
    const float* Wr3    = (const float*)d_in[15];
    const float* W_lin2 = (const float*)d_in[16];
    const float* b_lin2 = (const float*)d_in[17];
    const float* Wd1    = (const float*)d_in[18];
    const float* bd1    = (const float*)d_in[19];
    const float* Wd2    = (const float*)d_in[20];
    const float* bd2    = (const float*)d_in[21];
    float* out = (float*)d_out;

    const int E1 = in_sizes[2] / 2;
    const int E2 = in_sizes[3] / 2;
    const int E3 = in_sizes[4] / 2;

    float* ws = (float*)d_ws;
    size_t o = 0;
    float* art   = ws;      o += 1024;
    float* agg1  = ws + o;  o += NC;
    float* cnt1  = ws + o;  o += NC;
    float* agg2  = ws + o;  o += NC;
    float* cnt2  = ws + o;  o += NC;
    float* cnt3f = ws + o;  o += NC;
    float* buf   = ws + o;  o += 128;
    float* bvf   = ws + o;  o += 128;
    int* deg    = (int*)(ws + o); o += NC;
    int* pre    = (int*)(ws + o); o += NC;
    int* off    = (int*)(ws + o); o += NC;
    int* cursor = (int*)(ws + o); o += NC;
    int* blksum = (int*)(ws + o); o += 256;
    int* srcs   = (int*)(ws + o); o += 800000;
    int* eidx   = (int*)(ws + o); o += 800000;
    // fp16 arena
    _Float16* hws = (_Float16*)(ws + o);
    size_t ho = 0;
    _Float16* cxh    = hws + ho; ho += (size_t)NC * 256;
    _Float16* B1h    = hws + ho; ho += (size_t)NC * 128;
    _Float16* B2h    = hws + ho; ho += (size_t)NC * 128;
    _Float16* Wr1h   = hws + ho; ho += 128 * 256;
    _Float16* Wr2h   = hws + ho; ho += 128 * 128;
    _Float16* Wl3h   = hws + ho; ho += 128 * 128;
    _Float16* Wr3h   = hws + ho; ho += 128 * 256;
    _Float16* Wuh    = hws + ho; ho += 128 * 128;
    _Float16* Wvh    = hws + ho; ho += 128 * 128;

    hipMemsetAsync(agg1, 0, 4 * NC * sizeof(float), stream);   // agg1,cnt1,agg2,cnt2
    hipMemsetAsync(deg, 0, NC * sizeof(int), stream);

    // conversions + weight folding
    k_cvt4<<<(NC * 256 / 4 + 255) / 256, 256, 0, stream>>>(cx, cxh, NC * 256 / 4);
    k_cvt4<<<32, 256, 0, stream>>>(Wr1, Wr1h, 128 * 256 / 4);
    k_cvt4<<<16, 256, 0, stream>>>(Wr2, Wr2h, 128 * 128 / 4);
    k_cvt4<<<16, 256, 0, stream>>>(Wl3, Wl3h, 128 * 128 / 4);
    k_cvt4<<<32, 256, 0, stream>>>(Wr3, Wr3h, 128 * 256 / 4);
    k_wcomb<<<128, 128, 0, stream>>>(Wd1, W_lin2, Wuh, Wvh);
    k_bcomb<<<1, 128, 0, stream>>>(Wd1, b_lin2, bd1, buf, bvf);

    k_art<<<256, 256, 0, stream>>>(article_x, W_lin1, b_lin1, art);

    k_edge_scalar<<<512, 256, 0, stream>>>(e_wb, E1, art, agg1, cnt1);
    k_edge_scalar<<<512, 256, 0, stream>>>(e_mb, E2, art, agg2, cnt2);

    // CSR build for e_cc
    const int NB = (NC + 1023) / 1024;  // 98
    k_hist<<<512, 256, 0, stream>>>(e_cc, E3, deg);
    k_scan1<<<NB, 256, 0, stream>>>(deg, pre, blksum);
    k_scan2<<<1, 256, 0, stream>>>(blksum, NB);
    k_scan3<<<(NC + 255) / 256, 256, 0, stream>>>(pre, blksum, deg, off, cursor, cnt3f);
    k_csr_scatter<<<512, 256, 0, stream>>>(e_cc, E3, cursor, srcs, eidx);

    const int GB = (NC + 127) / 128;       // 782 blocks
    const int GW = (NC * 64 + 255) / 256;  // 1 wave per node

    // h1 = relu(cxh @ Wr1.T + bl1 + mean1*Wl1)                 -> B1h
    k_gemm_h<false, true, true, true><<<GB, 256, 0, stream>>>(
        cxh, 256, Wr1h, 256, nullptr, 0, nullptr, 0,
        bl1, agg1, cnt1, Wl1, nullptr, B1h, NC);
    // h2 = relu(h1 @ Wr2.T + bl2 + mean2*Wl2)                  -> B1h (in place)
    k_gemm_h<false, true, true, true><<<GB, 256, 0, stream>>>(
        B1h, 128, Wr2h, 128, nullptr, 0, nullptr, 0,
        bl2, agg2, cnt2, Wl2, nullptr, B1h, NC);
    // agg3 = CSR gather-sum of h2                              -> B2h
    k_csr_agg_h<<<GW, 256, 0, stream>>>(off, deg, srcs, B1h, B2h);
    // h3 = relu((agg3 @ Wl3.T)/cnt3 + bl3 + cxh @ Wr3.T)       -> B1h
    k_gemm_h<true, true, false, true><<<GB, 256, 0, stream>>>(
        B2h, 128, Wl3h, 128, cxh, 256, Wr3h, 256,
        bl3, nullptr, nullptr, nullptr, cnt3f, B1h, NC);
    // v = h3 @ Wv.T + bv                                       -> B2h  (z folded out)
    k_gemm_h<false, false, false, true><<<GB, 256, 0, stream>>>(
        B1h, 128, Wvh, 128, nullptr, 0, nullptr, 0,
        bvf, nullptr, nullptr, nullptr, nullptr, B2h, NC);
    // u = h3 @ Wu.T + bu                                       -> B1h (in place)
    k_gemm_h<false, false, false, true><<<GB, 256, 0, stream>>>(
        B1h, 128, Wuh, 128, nullptr, 0, nullptr, 0,
        buf, nullptr, nullptr, nullptr, nullptr, B1h, NC);

    k_decoder_h<<<GW, 256, 0, stream>>>(off, deg, srcs, eidx, B1h, B2h, Wd2, bd2, out);
}

// Round 7
// 469.692 us; speedup vs baseline: 2.2964x; 1.0898x over previous
//
#include <hip/hip_runtime.h>

#define NC 100000
#define NA 1024
#define FA 4096

typedef _Float16 half8 __attribute__((ext_vector_type(8)));
typedef _Float16 half4v __attribute__((ext_vector_type(4)));
typedef _Float16 half2v __attribute__((ext_vector_type(2)));
typedef float floatx4 __attribute__((ext_vector_type(4)));

// ---------------- fp32 -> fp16 convert (vector x4) ----------------
__global__ void k_cvt4(const float* __restrict__ in, _Float16* __restrict__ out, int n4) {
    int i = blockIdx.x * blockDim.x + threadIdx.x;
    if (i < n4) {
        float4 v = ((const float4*)in)[i];
        half4v h = {(_Float16)v.x, (_Float16)v.y, (_Float16)v.z, (_Float16)v.w};
        ((half4v*)out)[i] = h;
    }
}

// ---------------- weight folding: Wu = Wd1[:, :128] @ Wlin2, Wv = Wd1[:,128:] @ Wlin2 ----------------
__global__ void k_wcomb(const float* __restrict__ Wd1, const float* __restrict__ Wlin2,
                        _Float16* __restrict__ Wuh, _Float16* __restrict__ Wvh) {
    int i = blockIdx.x;      // 128 blocks = output row
    int j = threadIdx.x;     // 128 threads = output col (k of folded weight)
    float au = 0.f, av = 0.f;
    for (int m = 0; m < 128; ++m) {
        float wl = Wlin2[m * 128 + j];
        au = fmaf(Wd1[i * 256 + m], wl, au);
        av = fmaf(Wd1[i * 256 + 128 + m], wl, av);
    }
    Wuh[i * 128 + j] = (_Float16)au;
    Wvh[i * 128 + j] = (_Float16)av;
}

// ---------------- bias folding: bu = Wd1a@b2 + bd1, bv = Wd1b@b2 ----------------
__global__ void k_bcomb(const float* __restrict__ Wd1, const float* __restrict__ b2,
                        const float* __restrict__ bd1,
                        float* __restrict__ bu, float* __restrict__ bv) {
    int i = threadIdx.x;   // 128 threads
    float su = 0.f, sv = 0.f;
    for (int m = 0; m < 128; ++m) {
        float b = b2[m];
        su = fmaf(Wd1[i * 256 + m], b, su);
        sv = fmaf(Wd1[i * 256 + 128 + m], b, sv);
    }
    bu[i] = su + bd1[i];
    bv[i] = sv;
}

// ---------------- art[i] = article_x . W_lin1[i] + b_lin1[i] ----------------
__global__ void k_art(const float* __restrict__ ax, const float* __restrict__ W,
                      const float* __restrict__ b, float* __restrict__ art) {
    int wave = (blockIdx.x * blockDim.x + threadIdx.x) >> 6;
    int lane = threadIdx.x & 63;
    if (wave >= NA) return;
    const float* wr = W + (size_t)wave * FA;
    float s = 0.f;
    #pragma unroll
    for (int i = 0; i < FA; i += 256) {
        float4 a  = *(const float4*)&ax[i + 4 * lane];
        float4 wv = *(const float4*)&wr[i + 4 * lane];
        s += a.x * wv.x + a.y * wv.y + a.z * wv.z + a.w * wv.w;
    }
    for (int off = 32; off; off >>= 1) s += __shfl_down(s, off);
    if (lane == 0) art[wave] = s + b[wave];
}

// ---------------- both scalar scatters in one launch (grid split) ----------------
__global__ void k_edge_scalar2(const int* __restrict__ ei1, int E1,
                               const int* __restrict__ ei2, int E2,
                               const float* __restrict__ art,
                               float* __restrict__ agg1, float* __restrict__ cnt1,
                               float* __restrict__ agg2, float* __restrict__ cnt2) {
    int half = gridDim.x >> 1;
    const int* ei; int E; float* agg; float* cnt; int bid;
    if (blockIdx.x < half) { ei = ei1; E = E1; agg = agg1; cnt = cnt1; bid = blockIdx.x; }
    else { ei = ei2; E = E2; agg = agg2; cnt = cnt2; bid = blockIdx.x - half; }
    int t = bid * blockDim.x + threadIdx.x;
    int stride = half * blockDim.x;
    for (int e = t; e < E; e += stride) {
        int s = ei[e], d = ei[E + e];
        atomicAdd(&agg[d], art[s]);
        atomicAdd(&cnt[d], 1.0f);
    }
}

// ---------------- CSR build: histogram ----------------
__global__ void k_hist(const int* __restrict__ ei, int E, int* __restrict__ deg) {
    int t = blockIdx.x * blockDim.x + threadIdx.x;
    int stride = gridDim.x * blockDim.x;
    for (int e = t; e < E; e += stride) atomicAdd(&deg[ei[E + e]], 1);
}

// ---------------- CSR build: scan stage 1 ----------------
__global__ void k_scan1(const int* __restrict__ deg, int* __restrict__ pre,
                        int* __restrict__ blksum) {
    __shared__ int ts[256];
    int base = blockIdx.x * 1024 + threadIdx.x * 4;
    int v0 = 0, v1 = 0, v2 = 0, v3 = 0;
    if (base + 0 < NC) v0 = deg[base + 0];
    if (base + 1 < NC) v1 = deg[base + 1];
    if (base + 2 < NC) v2 = deg[base + 2];
    if (base + 3 < NC) v3 = deg[base + 3];
    int tsum = v0 + v1 + v2 + v3;
    ts[threadIdx.x] = tsum;
    __syncthreads();
    for (int off = 1; off < 256; off <<= 1) {
        int y = (threadIdx.x >= off) ? ts[threadIdx.x - off] : 0;
        __syncthreads();
        ts[threadIdx.x] += y;
        __syncthreads();
    }
    int excl = ts[threadIdx.x] - tsum;
    if (base + 0 < NC) pre[base + 0] = excl;
    if (base + 1 < NC) pre[base + 1] = excl + v0;
    if (base + 2 < NC) pre[base + 2] = excl + v0 + v1;
    if (base + 3 < NC) pre[base + 3] = excl + v0 + v1 + v2;
    if (threadIdx.x == 255) blksum[blockIdx.x] = ts[255];
}

// ---------------- CSR build: scan stage 2 ----------------
__global__ void k_scan2(int* __restrict__ blksum, int NB) {
    __shared__ int ts[256];
    int v = (threadIdx.x < NB) ? blksum[threadIdx.x] : 0;
    ts[threadIdx.x] = v;
    __syncthreads();
    for (int off = 1; off < 256; off <<= 1) {
        int y = (threadIdx.x >= off) ? ts[threadIdx.x - off] : 0;
        __syncthreads();
        ts[threadIdx.x] += y;
        __syncthreads();
    }
    if (threadIdx.x < NB) blksum[threadIdx.x] = ts[threadIdx.x] - v;  // exclusive
}

// ---------------- CSR build: scan stage 3 ----------------
__global__ void k_scan3(const int* __restrict__ pre, const int* __restrict__ blksum,
                        const int* __restrict__ deg, int* __restrict__ off,
                        int* __restrict__ cursor, float* __restrict__ cntf) {
    int i = blockIdx.x * blockDim.x + threadIdx.x;
    if (i < NC) {
        int o = pre[i] + blksum[i >> 10];
        off[i] = o;
        cursor[i] = o;
        cntf[i] = (float)deg[i];
    }
}

// ---------------- CSR build: scatter packed (src, edge-id) int2 ----------------
__global__ void k_csr_scatter(const int* __restrict__ ei, int E,
                              int* __restrict__ cursor, int2* __restrict__ se) {
    int t = blockIdx.x * blockDim.x + threadIdx.x;
    int stride = gridDim.x * blockDim.x;
    for (int e = t; e < E; e += stride) {
        int s = ei[e], d = ei[E + e];
        int p = atomicAdd(&cursor[d], 1);
        se[p] = make_int2(s, e);
    }
}

// ---------------- CSR aggregate (fp16 in, fp32 sum, fp16 out), prefetched indices ----------------
__global__ __launch_bounds__(256)
void k_csr_agg_h(const int* __restrict__ off, const int* __restrict__ deg,
                 const int2* __restrict__ se, const _Float16* __restrict__ h,
                 _Float16* __restrict__ agg) {
    int node = (blockIdx.x * blockDim.x + threadIdx.x) >> 6;
    int lane = threadIdx.x & 63;
    if (node >= NC) return;
    int b = off[node], d = deg[node];
    int dm = d < 64 ? d : 64;
    int sj = 0;
    if (lane < dm) sj = se[b + lane].x;
    float sx = 0.f, sy = 0.f;
    #pragma unroll 4
    for (int j = 0; j < dm; ++j) {
        int src = __shfl(sj, j);
        half2v m = *(const half2v*)&h[(size_t)src * 128 + 2 * lane];
        sx += (float)m[0]; sy += (float)m[1];
    }
    for (int j = 64; j < d; ++j) {
        int src = se[b + j].x;
        half2v m = *(const half2v*)&h[(size_t)src * 128 + 2 * lane];
        sx += (float)m[0]; sy += (float)m[1];
    }
    half2v r = {(_Float16)sx, (_Float16)sy};
    *(half2v*)&agg[(size_t)node * 128 + 2 * lane] = r;
}

// ---------------- fused encoder layers 1+2: h2 = relu(relu(cx@Wr1+e1)@Wr2+e2) ----------------
// Block 256 thr, BM=128. Phase1: K=256 (cx,Wr1) -> epilogue1 -> h1 tile in LDS ->
// Phase2: K=128 (h1,Wr2) -> out. LDS: Bh[128*40] + h1t[128*136] (Ah overlaps h1t).
__global__ __launch_bounds__(256)
void k_enc12(const _Float16* __restrict__ cxh, const _Float16* __restrict__ Wr1h,
             const _Float16* __restrict__ Wr2h,
             const float* __restrict__ bl1, const float* __restrict__ agg1,
             const float* __restrict__ cnt1, const float* __restrict__ Wl1,
             const float* __restrict__ bl2, const float* __restrict__ agg2,
             const float* __restrict__ cnt2, const float* __restrict__ Wl2,
             _Float16* __restrict__ out, int N)
{
    __shared__ _Float16 lds[128 * 40 + 128 * 136];
    _Float16* Bh  = lds;
    _Float16* Ah  = lds + 128 * 40;   // phase-1 only
    _Float16* h1t = lds + 128 * 40;   // phase-2 A source (overlaps Ah)

    const int t = threadIdx.x, lane = t & 63, w = t >> 6;
    const int rowbase = blockIdx.x * 128;
    const bool isA = t < 128;
    const int rr = isA ? t : t - 128;
    const int fr = lane & 15;
    const int kq = (lane >> 4) << 3;

    floatx4 zero4 = {0.f, 0.f, 0.f, 0.f};
    floatx4 acc[2][8];
    #pragma unroll
    for (int i = 0; i < 2; ++i)
        #pragma unroll
        for (int cf = 0; cf < 8; ++cf) acc[i][cf] = zero4;

    float4 p0, p1, p2, p3;
    {
        bool ok = true; const _Float16* base;
        if (isA) { int row = rowbase + rr; ok = row < N; base = ok ? &cxh[(size_t)row * 256] : Ah; }
        else base = &Wr1h[(size_t)rr * 256];
        const float4* s4 = (const float4*)base; float4 zf = make_float4(0.f, 0.f, 0.f, 0.f);
        p0 = ok ? s4[0] : zf; p1 = ok ? s4[1] : zf; p2 = ok ? s4[2] : zf; p3 = ok ? s4[3] : zf;
    }
    for (int tile = 0; tile < 8; ++tile) {
        float4* dst = (float4*)(isA ? &Ah[rr * 40] : &Bh[rr * 40]);
        dst[0] = p0; dst[1] = p1; dst[2] = p2; dst[3] = p3;
        __syncthreads();
        if (tile < 7) {
            int ko = (tile + 1) << 5;
            bool ok = true; const _Float16* base;
            if (isA) { int row = rowbase + rr; ok = row < N; base = ok ? &cxh[(size_t)row * 256 + ko] : Ah; }
            else base = &Wr1h[(size_t)rr * 256 + ko];
            const float4* s4 = (const float4*)base; float4 zf = make_float4(0.f, 0.f, 0.f, 0.f);
            p0 = ok ? s4[0] : zf; p1 = ok ? s4[1] : zf; p2 = ok ? s4[2] : zf; p3 = ok ? s4[3] : zf;
        }
        half8 af0 = *(const half8*)&Ah[(w * 32 + fr) * 40 + kq];
        half8 af1 = *(const half8*)&Ah[(w * 32 + 16 + fr) * 40 + kq];
        #pragma unroll
        for (int cf = 0; cf < 8; ++cf) {
            half8 bf = *(const half8*)&Bh[(cf * 16 + fr) * 40 + kq];
            acc[0][cf] = __builtin_amdgcn_mfma_f32_16x16x32_f16(af0, bf, acc[0][cf], 0, 0, 0);
            acc[1][cf] = __builtin_amdgcn_mfma_f32_16x16x32_f16(af1, bf, acc[1][cf], 0, 0, 0);
        }
        __syncthreads();
    }

    // epilogue 1 -> h1t (LDS), relu(acc + bl1 + mean1*Wl1)
    {
        float blc[8], wlc[8];
        #pragma unroll
        for (int cf = 0; cf < 8; ++cf) { int col = cf * 16 + fr; blc[cf] = bl1[col]; wlc[cf] = Wl1[col]; }
        #pragma unroll
        for (int i = 0; i < 2; ++i) {
            #pragma unroll
            for (int j = 0; j < 4; ++j) {
                int lrow = w * 32 + i * 16 + ((lane >> 4) << 2) + j;
                int grow = rowbase + lrow;
                float m = 0.f;
                if (grow < N) { float c = cnt1[grow]; c = c > 1.f ? c : 1.f; m = agg1[grow] / c; }
                #pragma unroll
                for (int cf = 0; cf < 8; ++cf) {
                    float v = acc[i][cf][j] + blc[cf] + m * wlc[cf];
                    v = fmaxf(v, 0.f);
                    h1t[lrow * 136 + cf * 16 + fr] = (_Float16)v;
                }
            }
        }
    }
    __syncthreads();

    // phase 2: K=128 over Wr2, A from h1t
    #pragma unroll
    for (int i = 0; i < 2; ++i)
        #pragma unroll
        for (int cf = 0; cf < 8; ++cf) acc[i][cf] = zero4;
    if (!isA) {
        const float4* s4 = (const float4*)&Wr2h[(size_t)rr * 128];
        p0 = s4[0]; p1 = s4[1]; p2 = s4[2]; p3 = s4[3];
    }
    for (int tt = 0; tt < 4; ++tt) {
        if (!isA) { float4* dst = (float4*)&Bh[rr * 40]; dst[0] = p0; dst[1] = p1; dst[2] = p2; dst[3] = p3; }
        __syncthreads();
        if (!isA && tt < 3) {
            const float4* s4 = (const float4*)&Wr2h[(size_t)rr * 128 + ((tt + 1) << 5)];
            p0 = s4[0]; p1 = s4[1]; p2 = s4[2]; p3 = s4[3];
        }
        half8 af0 = *(const half8*)&h1t[(w * 32 + fr) * 136 + (tt << 5) + kq];
        half8 af1 = *(const half8*)&h1t[(w * 32 + 16 + fr) * 136 + (tt << 5) + kq];
        #pragma unroll
        for (int cf = 0; cf < 8; ++cf) {
            half8 bf = *(const half8*)&Bh[(cf * 16 + fr) * 40 + kq];
            acc[0][cf] = __builtin_amdgcn_mfma_f32_16x16x32_f16(af0, bf, acc[0][cf], 0, 0, 0);
            acc[1][cf] = __builtin_amdgcn_mfma_f32_16x16x32_f16(af1, bf, acc[1][cf], 0, 0, 0);
        }
        __syncthreads();
    }

    // epilogue 2 -> out, relu(acc + bl2 + mean2*Wl2)
    {
        float blc[8], wlc[8];
        #pragma unroll
        for (int cf = 0; cf < 8; ++cf) { int col = cf * 16 + fr; blc[cf] = bl2[col]; wlc[cf] = Wl2[col]; }
        #pragma unroll
        for (int i = 0; i < 2; ++i) {
            #pragma unroll
            for (int j = 0; j < 4; ++j) {
                int grow = rowbase + w * 32 + i * 16 + ((lane >> 4) << 2) + j;
                if (grow < N) {
                    float c = cnt2[grow]; c = c > 1.f ? c : 1.f;
                    float m = agg2[grow] / c;
                    #pragma unroll
                    for (int cf = 0; cf < 8; ++cf) {
                        float v = acc[i][cf][j] + blc[cf] + m * wlc[cf];
                        v = fmaxf(v, 0.f);
                        out[(size_t)grow * 128 + cf * 16 + fr] = (_Float16)v;
                    }
                }
            }
        }
    }
}

// ---------------- fused encoder layer 3 + u/v heads ----------------
// Phase1: h3 = relu((agg3@Wl3)/cnt + cx@Wr3 + bl3) -> LDS; Phase2: u=h3@Wu+bu; Phase3: v=h3@Wv+bv.
__global__ __launch_bounds__(256)
void k_enc3uv(const _Float16* __restrict__ aggh, const _Float16* __restrict__ Wl3h,
              const _Float16* __restrict__ cxh, const _Float16* __restrict__ Wr3h,
              const float* __restrict__ bl3, const float* __restrict__ rcnt,
              const _Float16* __restrict__ Wuh, const float* __restrict__ bu,
              const _Float16* __restrict__ Wvh, const float* __restrict__ bv,
              _Float16* __restrict__ uout, _Float16* __restrict__ vout, int N)
{
    __shared__ _Float16 lds[128 * 40 + 128 * 136];
    _Float16* Bh  = lds;
    _Float16* Ah  = lds + 128 * 40;
    _Float16* h3t = lds + 128 * 40;

    const int t = threadIdx.x, lane = t & 63, w = t >> 6;
    const int rowbase = blockIdx.x * 128;
    const bool isA = t < 128;
    const int rr = isA ? t : t - 128;
    const int fr = lane & 15;
    const int kq = (lane >> 4) << 3;

    floatx4 zero4 = {0.f, 0.f, 0.f, 0.f};
    floatx4 acc[2][8];
    #pragma unroll
    for (int i = 0; i < 2; ++i)
        #pragma unroll
        for (int cf = 0; cf < 8; ++cf) acc[i][cf] = zero4;

    float4 p0, p1, p2, p3;
    {
        bool ok = true; const _Float16* base;
        if (isA) { int row = rowbase + rr; ok = row < N; base = ok ? &aggh[(size_t)row * 128] : Ah; }
        else base = &Wl3h[(size_t)rr * 128];
        const float4* s4 = (const float4*)base; float4 zf = make_float4(0.f, 0.f, 0.f, 0.f);
        p0 = ok ? s4[0] : zf; p1 = ok ? s4[1] : zf; p2 = ok ? s4[2] : zf; p3 = ok ? s4[3] : zf;
    }
    for (int tile = 0; tile < 12; ++tile) {
        float4* dst = (float4*)(isA ? &Ah[rr * 40] : &Bh[rr * 40]);
        dst[0] = p0; dst[1] = p1; dst[2] = p2; dst[3] = p3;
        __syncthreads();
        if (tile < 11) {
            int tn = tile + 1;
            bool ok = true; const _Float16* base;
            if (tn < 4) {
                int ko = tn << 5;
                if (isA) { int row = rowbase + rr; ok = row < N; base = ok ? &aggh[(size_t)row * 128 + ko] : Ah; }
                else base = &Wl3h[(size_t)rr * 128 + ko];
            } else {
                int ko = (tn - 4) << 5;
                if (isA) { int row = rowbase + rr; ok = row < N; base = ok ? &cxh[(size_t)row * 256 + ko] : Ah; }
                else base = &Wr3h[(size_t)rr * 256 + ko];
            }
            const float4* s4 = (const float4*)base; float4 zf = make_float4(0.f, 0.f, 0.f, 0.f);
            p0 = ok ? s4[0] : zf; p1 = ok ? s4[1] : zf; p2 = ok ? s4[2] : zf; p3 = ok ? s4[3] : zf;
        }
        half8 af0 = *(const half8*)&Ah[(w * 32 + fr) * 40 + kq];
        half8 af1 = *(const half8*)&Ah[(w * 32 + 16 + fr) * 40 + kq];
        #pragma unroll
        for (int cf = 0; cf < 8; ++cf) {
            half8 bf = *(const half8*)&Bh[(cf * 16 + fr) * 40 + kq];
            acc[0][cf] = __builtin_amdgcn_mfma_f32_16x16x32_f16(af0, bf, acc[0][cf], 0, 0, 0);
            acc[1][cf] = __builtin_amdgcn_mfma_f32_16x16x32_f16(af1, bf, acc[1][cf], 0, 0, 0);
        }
        if (tile == 3) {
            #pragma unroll
            for (int i = 0; i < 2; ++i)
                #pragma unroll
                for (int j = 0; j < 4; ++j) {
                    int row = rowbase + w * 32 + i * 16 + ((lane >> 4) << 2) + j;
                    float c = (row < N) ? rcnt[row] : 1.f;
                    c = c > 1.f ? c : 1.f;
                    float inv = 1.f / c;
                    #pragma unroll
                    for (int cf = 0; cf < 8; ++cf) acc[i][cf][j] *= inv;
                }
        }
        __syncthreads();
    }

    // epilogue 1 -> h3t (LDS): relu(acc + bl3)
    {
        float blc[8];
        #pragma unroll
        for (int cf = 0; cf < 8; ++cf) blc[cf] = bl3[cf * 16 + fr];
        #pragma unroll
        for (int i = 0; i < 2; ++i) {
            #pragma unroll
            for (int j = 0; j < 4; ++j) {
                int lrow = w * 32 + i * 16 + ((lane >> 4) << 2) + j;
                #pragma unroll
                for (int cf = 0; cf < 8; ++cf) {
                    float v = acc[i][cf][j] + blc[cf];
                    v = fmaxf(v, 0.f);
                    h3t[lrow * 136 + cf * 16 + fr] = (_Float16)v;
                }
            }
        }
    }
    __syncthreads();

    // phases 2 (u) and 3 (v): K=128 from h3t
    for (int ph = 0; ph < 2; ++ph) {
        const _Float16* Wp = ph ? Wvh : Wuh;
        const float* bp = ph ? bv : bu;
        _Float16* op = ph ? vout : uout;
        #pragma unroll
        for (int i = 0; i < 2; ++i)
            #pragma unroll
            for (int cf = 0; cf < 8; ++cf) acc[i][cf] = zero4;
        if (!isA) {
            const float4* s4 = (const float4*)&Wp[(size_t)rr * 128];
            p0 = s4[0]; p1 = s4[1]; p2 = s4[2]; p3 = s4[3];
        }
        for (int tt = 0; tt < 4; ++tt) {
            if (!isA) { float4* dst = (float4*)&Bh[rr * 40]; dst[0] = p0; dst[1] = p1; dst[2] = p2; dst[3] = p3; }
            __syncthreads();
            if (!isA && tt < 3) {
                const float4* s4 = (const float4*)&Wp[(size_t)rr * 128 + ((tt + 1) << 5)];
                p0 = s4[0]; p1 = s4[1]; p2 = s4[2]; p3 = s4[3];
            }
            half8 af0 = *(const half8*)&h3t[(w * 32 + fr) * 136 + (tt << 5) + kq];
            half8 af1 = *(const half8*)&h3t[(w * 32 + 16 + fr) * 136 + (tt << 5) + kq];
            #pragma unroll
            for (int cf = 0; cf < 8; ++cf) {
                half8 bf = *(const half8*)&Bh[(cf * 16 + fr) * 40 + kq];
                acc[0][cf] = __builtin_amdgcn_mfma_f32_16x16x32_f16(af0, bf, acc[0][cf], 0, 0, 0);
                acc[1][cf] = __builtin_amdgcn_mfma_f32_16x16x32_f16(af1, bf, acc[1][cf], 0, 0, 0);
            }
            __syncthreads();
        }
        float bc[8];
        #pragma unroll
        for (int cf = 0; cf < 8; ++cf) bc[cf] = bp[cf * 16 + fr];
        #pragma unroll
        for (int i = 0; i < 2; ++i) {
            #pragma unroll
            for (int j = 0; j < 4; ++j) {
                int grow = rowbase + w * 32 + i * 16 + ((lane >> 4) << 2) + j;
                if (grow < N) {
                    #pragma unroll
                    for (int cf = 0; cf < 8; ++cf)
                        op[(size_t)grow * 128 + cf * 16 + fr] = (_Float16)(acc[i][cf][j] + bc[cf]);
                }
            }
        }
    }
}

// ---------------- decoder over CSR (fp16 u,v), prefetched packed indices ----------------
__global__ __launch_bounds__(256)
void k_decoder_h(const int* __restrict__ off, const int* __restrict__ deg,
                 const int2* __restrict__ se,
                 const _Float16* __restrict__ u, const _Float16* __restrict__ v,
                 const float* __restrict__ wd2, const float* __restrict__ bd2,
                 float* __restrict__ out) {
    int node = (blockIdx.x * blockDim.x + threadIdx.x) >> 6;
    if (node >= NC) return;
    int lane = threadIdx.x & 63;
    int g = lane >> 3, s = lane & 7;

    float wf[16], vf[16];
    #pragma unroll
    for (int q = 0; q < 16; ++q) wf[q] = wd2[s * 16 + q];
    {
        half8 va = *(const half8*)&v[(size_t)node * 128 + s * 16];
        half8 vb = *(const half8*)&v[(size_t)node * 128 + s * 16 + 8];
        #pragma unroll
        for (int q = 0; q < 8; ++q) { vf[q] = (float)va[q]; vf[8 + q] = (float)vb[q]; }
    }
    float bb = bd2[0];

    int b = off[node], d = deg[node];
    int dm = d < 64 ? d : 64;
    int sj = 0, ej = 0;
    if (lane < dm) { int2 p = se[b + lane]; sj = p.x; ej = p.y; }

    for (int jb = 0; jb < d; jb += 8) {
        int j = jb + g;
        float p = 0.f;
        int eid = 0;
        bool act = j < d;
        int src = 0;
        if (jb < 64) {             // uniform branch (jb multiple of 8)
            src = __shfl(sj, j);
            eid = __shfl(ej, j);
        } else if (act) {
            int2 pr = se[b + j];
            src = pr.x; eid = pr.y;
        }
        if (act) {
            half8 ua = *(const half8*)&u[(size_t)src * 128 + s * 16];
            half8 ub = *(const half8*)&u[(size_t)src * 128 + s * 16 + 8];
            #pragma unroll
            for (int q = 0; q < 8; ++q) {
                p = fmaf(wf[q],     fmaxf((float)ua[q] + vf[q],     0.f), p);
                p = fmaf(wf[8 + q], fmaxf((float)ub[q] + vf[8 + q], 0.f), p);
            }
        }
        p += __shfl_xor(p, 1);
        p += __shfl_xor(p, 2);
        p += __shfl_xor(p, 4);
        if (act && s == 0) out[eid] = p + bb;
    }
}

extern "C" void kernel_launch(void* const* d_in, const int* in_sizes, int n_in,
                              void* d_out, int out_size, void* d_ws, size_t ws_size,
                              hipStream_t stream) {
    const float* article_x = (const float*)d_in[0];
    const float* cx     = (const float*)d_in[1];
    const int*   e_wb   = (const int*)d_in[2];
    const int*   e_mb   = (const int*)d_in[3];
    const int*   e_cc   = (const int*)d_in[4];
    const float* W_lin1 = (const float*)d_in[5];
    const float* b_lin1 = (const float*)d_in[6];
    const float* Wl1    = (const float*)d_in[7];
    const float* bl1    = (const float*)d_in[8];
    const float* Wr1    = (const float*)d_in[9];
    const float* Wl2    = (const float*)d_in[10];
    const float* bl2    = (const float*)d_in[11];
    const float* Wr2    = (const float*)d_in[12];
    const float* Wl3    = (const float*)d_in[13];
    const float* bl3    = (const float*)d_in[14];
    const float* Wr3    = (const float*)d_in[15];
    const float* W_lin2 = (const float*)d_in[16];
    const float* b_lin2 = (const float*)d_in[17];
    const float* Wd1    = (const float*)d_in[18];
    const float* bd1    = (const float*)d_in[19];
    const float* Wd2    = (const float*)d_in[20];
    const float* bd2    = (const float*)d_in[21];
    float* out = (float*)d_out;

    const int E1 = in_sizes[2] / 2;
    const int E2 = in_sizes[3] / 2;
    const int E3 = in_sizes[4] / 2;

    float* ws = (float*)d_ws;
    size_t o = 0;
    float* art   = ws;      o += 1024;
    float* agg1  = ws + o;  o += NC;
    float* cnt1  = ws + o;  o += NC;
    float* agg2  = ws + o;  o += NC;
    float* cnt2  = ws + o;  o += NC;
    float* cnt3f = ws + o;  o += NC;
    float* buf   = ws + o;  o += 128;
    float* bvf   = ws + o;  o += 128;
    int* deg    = (int*)(ws + o); o += NC;
    int* pre    = (int*)(ws + o); o += NC;
    int* off    = (int*)(ws + o); o += NC;
    int* cursor = (int*)(ws + o); o += NC;
    int* blksum = (int*)(ws + o); o += 256;
    int2* se    = (int2*)(ws + o); o += 2 * 800000;
    // fp16 arena
    _Float16* hws = (_Float16*)(ws + o);
    size_t ho = 0;
    _Float16* cxh    = hws + ho; ho += (size_t)NC * 256;
    _Float16* B1h    = hws + ho; ho += (size_t)NC * 128;
    _Float16* B2h    = hws + ho; ho += (size_t)NC * 128;
    _Float16* Wr1h   = hws + ho; ho += 128 * 256;
    _Float16* Wr2h   = hws + ho; ho += 128 * 128;
    _Float16* Wl3h   = hws + ho; ho += 128 * 128;
    _Float16* Wr3h   = hws + ho; ho += 128 * 256;
    _Float16* Wuh    = hws + ho; ho += 128 * 128;
    _Float16* Wvh    = hws + ho; ho += 128 * 128;

    hipMemsetAsync(agg1, 0, 4 * NC * sizeof(float), stream);   // agg1,cnt1,agg2,cnt2
    hipMemsetAsync(deg, 0, NC * sizeof(int), stream);

    // conversions + weight/bias folding
    k_cvt4<<<(NC * 256 / 4 + 255) / 256, 256, 0, stream>>>(cx, cxh, NC * 256 / 4);
    k_cvt4<<<32, 256, 0, stream>>>(Wr1, Wr1h, 128 * 256 / 4);
    k_cvt4<<<16, 256, 0, stream>>>(Wr2, Wr2h, 128 * 128 / 4);
    k_cvt4<<<16, 256, 0, stream>>>(Wl3, Wl3h, 128 * 128 / 4);
    k_cvt4<<<32, 256, 0, stream>>>(Wr3, Wr3h, 128 * 256 / 4);
    k_wcomb<<<128, 128, 0, stream>>>(Wd1, W_lin2, Wuh, Wvh);
    k_bcomb<<<1, 128, 0, stream>>>(Wd1, b_lin2, bd1, buf, bvf);

    k_art<<<256, 256, 0, stream>>>(article_x, W_lin1, b_lin1, art);

    k_edge_scalar2<<<1024, 256, 0, stream>>>(e_wb, E1, e_mb, E2, art, agg1, cnt1, agg2, cnt2);

    // CSR build for e_cc
    const int NB = (NC + 1023) / 1024;  // 98
    k_hist<<<512, 256, 0, stream>>>(e_cc, E3, deg);
    k_scan1<<<NB, 256, 0, stream>>>(deg, pre, blksum);
    k_scan2<<<1, 256, 0, stream>>>(blksum, NB);
    k_scan3<<<(NC + 255) / 256, 256, 0, stream>>>(pre, blksum, deg, off, cursor, cnt3f);
    k_csr_scatter<<<512, 256, 0, stream>>>(e_cc, E3, cursor, se);

    const int GB = (NC + 127) / 128;       // 782 blocks
    const int GW = (NC * 64 + 255) / 256;  // 1 wave per node

    // h2 = enc layers 1+2 fused                       -> B1h
    k_enc12<<<GB, 256, 0, stream>>>(cxh, Wr1h, Wr2h,
                                    bl1, agg1, cnt1, Wl1,
                                    bl2, agg2, cnt2, Wl2, B1h, NC);
    // agg3 = CSR gather-sum of h2                     -> B2h
    k_csr_agg_h<<<GW, 256, 0, stream>>>(off, deg, se, B1h, B2h);
    // h3 + u/v heads fused: u -> B1h, v -> B2h
    k_enc3uv<<<GB, 256, 0, stream>>>(B2h, Wl3h, cxh, Wr3h,
                                     bl3, cnt3f, Wuh, buf, Wvh, bvf,
                                     B1h, B2h, NC);

    k_decoder_h<<<GW, 256, 0, stream>>>(off, deg, se, B1h, B2h, Wd2, bd2, out);
}

// Round 8
// 408.784 us; speedup vs baseline: 2.6385x; 1.1490x over previous
//
#include <hip/hip_runtime.h>

#define NC 100000
#define NA 1024
#define FA 4096

typedef _Float16 half8 __attribute__((ext_vector_type(8)));
typedef _Float16 half4v __attribute__((ext_vector_type(4)));
typedef _Float16 half2v __attribute__((ext_vector_type(2)));
typedef float floatx4 __attribute__((ext_vector_type(4)));

// ================= device helpers for k_front segments =================
__device__ __forceinline__ void cvt_range(const float* __restrict__ in,
                                          _Float16* __restrict__ out, int n4,
                                          int bid, int nb) {
    int t = bid * 256 + threadIdx.x;
    int stride = nb * 256;
    for (int i = t; i < n4; i += stride) {
        float4 v = ((const float4*)in)[i];
        half4v h = {(_Float16)v.x, (_Float16)v.y, (_Float16)v.z, (_Float16)v.w};
        ((half4v*)out)[i] = h;
    }
}

__device__ __forceinline__ void edge_seg(const int* __restrict__ ei, int E,
                                         const float* __restrict__ art,
                                         float* __restrict__ ac, int bid, int nb) {
    int t = bid * 256 + threadIdx.x;
    int stride = nb * 256;
    for (int e = t; e < E; e += stride) {
        int s = ei[e], d = ei[E + e];
        atomicAdd(&ac[2 * d], art[s]);       // same 8B as cnt -> same sector
        atomicAdd(&ac[2 * d + 1], 1.0f);
    }
}

__device__ __forceinline__ void hist_seg(const int* __restrict__ ei, int E,
                                         int* __restrict__ deg, int bid, int nb) {
    int t = bid * 256 + threadIdx.x;
    int stride = nb * 256;
    for (int e = t; e < E; e += stride) atomicAdd(&deg[ei[E + e]], 1);
}

__device__ __forceinline__ void wcomb_seg(const float* __restrict__ Wd1,
                                          const float* __restrict__ Wlin2,
                                          _Float16* __restrict__ Wuh,
                                          _Float16* __restrict__ Wvh, int bid) {
    int i = bid * 2 + (threadIdx.x >> 7);   // 2 rows per block
    int j = threadIdx.x & 127;
    float au = 0.f, av = 0.f;
    for (int m = 0; m < 128; ++m) {
        float wl = Wlin2[m * 128 + j];
        au = fmaf(Wd1[i * 256 + m], wl, au);
        av = fmaf(Wd1[i * 256 + 128 + m], wl, av);
    }
    Wuh[i * 128 + j] = (_Float16)au;
    Wvh[i * 128 + j] = (_Float16)av;
}

__device__ __forceinline__ void bcomb_seg(const float* __restrict__ Wd1,
                                          const float* __restrict__ b2,
                                          const float* __restrict__ bd1,
                                          float* __restrict__ bu, float* __restrict__ bv) {
    int i = threadIdx.x;
    if (i >= 128) return;
    float su = 0.f, sv = 0.f;
    for (int m = 0; m < 128; ++m) {
        float b = b2[m];
        su = fmaf(Wd1[i * 256 + m], b, su);
        sv = fmaf(Wd1[i * 256 + 128 + m], b, sv);
    }
    bu[i] = su + bd1[i];
    bv[i] = sv;
}

// ================= mega front kernel: edges + hist + cvts + folding =================
#define FRONT_WB   1024
#define FRONT_MB   1024
#define FRONT_HIST 768
#define FRONT_WCVT 96
#define FRONT_WCOMB 64
#define FRONT_BCOMB 1
#define FRONT_CVT  8192
#define FRONT_TOTAL (FRONT_WB + FRONT_MB + FRONT_HIST + FRONT_WCVT + FRONT_WCOMB + FRONT_BCOMB + FRONT_CVT)

__global__ __launch_bounds__(256)
void k_front(const int* __restrict__ e_wb, int E1,
             const int* __restrict__ e_mb, int E2,
             const int* __restrict__ e_cc, int E3,
             const float* __restrict__ art,
             float* __restrict__ ac1, float* __restrict__ ac2,
             int* __restrict__ deg,
             const float* __restrict__ Wr1, _Float16* __restrict__ Wr1h,
             const float* __restrict__ Wr2, _Float16* __restrict__ Wr2h,
             const float* __restrict__ Wl3, _Float16* __restrict__ Wl3h,
             const float* __restrict__ Wr3, _Float16* __restrict__ Wr3h,
             const float* __restrict__ Wd1, const float* __restrict__ Wlin2,
             _Float16* __restrict__ Wuh, _Float16* __restrict__ Wvh,
             const float* __restrict__ b2, const float* __restrict__ bd1,
             float* __restrict__ bu, float* __restrict__ bv,
             const float* __restrict__ cx, _Float16* __restrict__ cxh)
{
    int b = blockIdx.x;
    if (b < FRONT_WB) { edge_seg(e_wb, E1, art, ac1, b, FRONT_WB); return; }
    b -= FRONT_WB;
    if (b < FRONT_MB) { edge_seg(e_mb, E2, art, ac2, b, FRONT_MB); return; }
    b -= FRONT_MB;
    if (b < FRONT_HIST) { hist_seg(e_cc, E3, deg, b, FRONT_HIST); return; }
    b -= FRONT_HIST;
    if (b < FRONT_WCVT) {
        if (b < 32) cvt_range(Wr1, Wr1h, 8192, b, 32);
        else if (b < 48) cvt_range(Wr2, Wr2h, 4096, b - 32, 16);
        else if (b < 64) cvt_range(Wl3, Wl3h, 4096, b - 48, 16);
        else cvt_range(Wr3, Wr3h, 8192, b - 64, 32);
        return;
    }
    b -= FRONT_WCVT;
    if (b < FRONT_WCOMB) { wcomb_seg(Wd1, Wlin2, Wuh, Wvh, b); return; }
    b -= FRONT_WCOMB;
    if (b < FRONT_BCOMB) { bcomb_seg(Wd1, b2, bd1, bu, bv); return; }
    b -= FRONT_BCOMB;
    cvt_range(cx, cxh, NC * 64, b, FRONT_CVT);
}

// ---------------- art[i] = article_x . W_lin1[i] + b_lin1[i] ----------------
__global__ void k_art(const float* __restrict__ ax, const float* __restrict__ W,
                      const float* __restrict__ b, float* __restrict__ art) {
    int wave = (blockIdx.x * blockDim.x + threadIdx.x) >> 6;
    int lane = threadIdx.x & 63;
    if (wave >= NA) return;
    const float* wr = W + (size_t)wave * FA;
    float s = 0.f;
    #pragma unroll
    for (int i = 0; i < FA; i += 256) {
        float4 a  = *(const float4*)&ax[i + 4 * lane];
        float4 wv = *(const float4*)&wr[i + 4 * lane];
        s += a.x * wv.x + a.y * wv.y + a.z * wv.z + a.w * wv.w;
    }
    for (int off = 32; off; off >>= 1) s += __shfl_down(s, off);
    if (lane == 0) art[wave] = s + b[wave];
}

// ---------------- CSR build: scan stage 1 ----------------
__global__ void k_scan1(const int* __restrict__ deg, int* __restrict__ pre,
                        int* __restrict__ blksum) {
    __shared__ int ts[256];
    int base = blockIdx.x * 1024 + threadIdx.x * 4;
    int v0 = 0, v1 = 0, v2 = 0, v3 = 0;
    if (base + 0 < NC) v0 = deg[base + 0];
    if (base + 1 < NC) v1 = deg[base + 1];
    if (base + 2 < NC) v2 = deg[base + 2];
    if (base + 3 < NC) v3 = deg[base + 3];
    int tsum = v0 + v1 + v2 + v3;
    ts[threadIdx.x] = tsum;
    __syncthreads();
    for (int off = 1; off < 256; off <<= 1) {
        int y = (threadIdx.x >= off) ? ts[threadIdx.x - off] : 0;
        __syncthreads();
        ts[threadIdx.x] += y;
        __syncthreads();
    }
    int excl = ts[threadIdx.x] - tsum;
    if (base + 0 < NC) pre[base + 0] = excl;
    if (base + 1 < NC) pre[base + 1] = excl + v0;
    if (base + 2 < NC) pre[base + 2] = excl + v0 + v1;
    if (base + 3 < NC) pre[base + 3] = excl + v0 + v1 + v2;
    if (threadIdx.x == 255) blksum[blockIdx.x] = ts[255];
}

// ---------------- CSR build: scan stage 2 ----------------
__global__ void k_scan2(int* __restrict__ blksum, int NB) {
    __shared__ int ts[256];
    int v = (threadIdx.x < NB) ? blksum[threadIdx.x] : 0;
    ts[threadIdx.x] = v;
    __syncthreads();
    for (int off = 1; off < 256; off <<= 1) {
        int y = (threadIdx.x >= off) ? ts[threadIdx.x - off] : 0;
        __syncthreads();
        ts[threadIdx.x] += y;
        __syncthreads();
    }
    if (threadIdx.x < NB) blksum[threadIdx.x] = ts[threadIdx.x] - v;  // exclusive
}

// ---------------- CSR build: scan stage 3 ----------------
__global__ void k_scan3(const int* __restrict__ pre, const int* __restrict__ blksum,
                        const int* __restrict__ deg, int* __restrict__ off,
                        int* __restrict__ cursor, float* __restrict__ cntf) {
    int i = blockIdx.x * blockDim.x + threadIdx.x;
    if (i < NC) {
        int o = pre[i] + blksum[i >> 10];
        off[i] = o;
        cursor[i] = o;
        cntf[i] = (float)deg[i];
    }
}

// ================= enc12 body (device) =================
__device__ __forceinline__
void enc12_body(_Float16* lds, int blk,
                const _Float16* __restrict__ cxh, const _Float16* __restrict__ Wr1h,
                const _Float16* __restrict__ Wr2h,
                const float* __restrict__ bl1, const float2* __restrict__ ac1,
                const float* __restrict__ Wl1,
                const float* __restrict__ bl2, const float2* __restrict__ ac2,
                const float* __restrict__ Wl2,
                _Float16* __restrict__ out, int N)
{
    _Float16* Bh  = lds;
    _Float16* Ah  = lds + 128 * 40;
    _Float16* h1t = lds + 128 * 40;

    const int t = threadIdx.x, lane = t & 63, w = t >> 6;
    const int rowbase = blk * 128;
    const bool isA = t < 128;
    const int rr = isA ? t : t - 128;
    const int fr = lane & 15;
    const int kq = (lane >> 4) << 3;

    floatx4 zero4 = {0.f, 0.f, 0.f, 0.f};
    floatx4 acc[2][8];
    #pragma unroll
    for (int i = 0; i < 2; ++i)
        #pragma unroll
        for (int cf = 0; cf < 8; ++cf) acc[i][cf] = zero4;

    float4 p0, p1, p2, p3;
    {
        bool ok = true; const _Float16* base;
        if (isA) { int row = rowbase + rr; ok = row < N; base = ok ? &cxh[(size_t)row * 256] : Ah; }
        else base = &Wr1h[(size_t)rr * 256];
        const float4* s4 = (const float4*)base; float4 zf = make_float4(0.f, 0.f, 0.f, 0.f);
        p0 = ok ? s4[0] : zf; p1 = ok ? s4[1] : zf; p2 = ok ? s4[2] : zf; p3 = ok ? s4[3] : zf;
    }
    for (int tile = 0; tile < 8; ++tile) {
        float4* dst = (float4*)(isA ? &Ah[rr * 40] : &Bh[rr * 40]);
        dst[0] = p0; dst[1] = p1; dst[2] = p2; dst[3] = p3;
        __syncthreads();
        if (tile < 7) {
            int ko = (tile + 1) << 5;
            bool ok = true; const _Float16* base;
            if (isA) { int row = rowbase + rr; ok = row < N; base = ok ? &cxh[(size_t)row * 256 + ko] : Ah; }
            else base = &Wr1h[(size_t)rr * 256 + ko];
            const float4* s4 = (const float4*)base; float4 zf = make_float4(0.f, 0.f, 0.f, 0.f);
            p0 = ok ? s4[0] : zf; p1 = ok ? s4[1] : zf; p2 = ok ? s4[2] : zf; p3 = ok ? s4[3] : zf;
        }
        half8 af0 = *(const half8*)&Ah[(w * 32 + fr) * 40 + kq];
        half8 af1 = *(const half8*)&Ah[(w * 32 + 16 + fr) * 40 + kq];
        #pragma unroll
        for (int cf = 0; cf < 8; ++cf) {
            half8 bf = *(const half8*)&Bh[(cf * 16 + fr) * 40 + kq];
            acc[0][cf] = __builtin_amdgcn_mfma_f32_16x16x32_f16(af0, bf, acc[0][cf], 0, 0, 0);
            acc[1][cf] = __builtin_amdgcn_mfma_f32_16x16x32_f16(af1, bf, acc[1][cf], 0, 0, 0);
        }
        __syncthreads();
    }

    {
        float blc[8], wlc[8];
        #pragma unroll
        for (int cf = 0; cf < 8; ++cf) { int col = cf * 16 + fr; blc[cf] = bl1[col]; wlc[cf] = Wl1[col]; }
        #pragma unroll
        for (int i = 0; i < 2; ++i) {
            #pragma unroll
            for (int j = 0; j < 4; ++j) {
                int lrow = w * 32 + i * 16 + ((lane >> 4) << 2) + j;
                int grow = rowbase + lrow;
                float m = 0.f;
                if (grow < N) { float2 a = ac1[grow]; float c = a.y > 1.f ? a.y : 1.f; m = a.x / c; }
                #pragma unroll
                for (int cf = 0; cf < 8; ++cf) {
                    float v = acc[i][cf][j] + blc[cf] + m * wlc[cf];
                    v = fmaxf(v, 0.f);
                    h1t[lrow * 136 + cf * 16 + fr] = (_Float16)v;
                }
            }
        }
    }
    __syncthreads();

    #pragma unroll
    for (int i = 0; i < 2; ++i)
        #pragma unroll
        for (int cf = 0; cf < 8; ++cf) acc[i][cf] = zero4;
    if (!isA) {
        const float4* s4 = (const float4*)&Wr2h[(size_t)rr * 128];
        p0 = s4[0]; p1 = s4[1]; p2 = s4[2]; p3 = s4[3];
    }
    for (int tt = 0; tt < 4; ++tt) {
        if (!isA) { float4* dst = (float4*)&Bh[rr * 40]; dst[0] = p0; dst[1] = p1; dst[2] = p2; dst[3] = p3; }
        __syncthreads();
        if (!isA && tt < 3) {
            const float4* s4 = (const float4*)&Wr2h[(size_t)rr * 128 + ((tt + 1) << 5)];
            p0 = s4[0]; p1 = s4[1]; p2 = s4[2]; p3 = s4[3];
        }
        half8 af0 = *(const half8*)&h1t[(w * 32 + fr) * 136 + (tt << 5) + kq];
        half8 af1 = *(const half8*)&h1t[(w * 32 + 16 + fr) * 136 + (tt << 5) + kq];
        #pragma unroll
        for (int cf = 0; cf < 8; ++cf) {
            half8 bf = *(const half8*)&Bh[(cf * 16 + fr) * 40 + kq];
            acc[0][cf] = __builtin_amdgcn_mfma_f32_16x16x32_f16(af0, bf, acc[0][cf], 0, 0, 0);
            acc[1][cf] = __builtin_amdgcn_mfma_f32_16x16x32_f16(af1, bf, acc[1][cf], 0, 0, 0);
        }
        __syncthreads();
    }

    {
        float blc[8], wlc[8];
        #pragma unroll
        for (int cf = 0; cf < 8; ++cf) { int col = cf * 16 + fr; blc[cf] = bl2[col]; wlc[cf] = Wl2[col]; }
        #pragma unroll
        for (int i = 0; i < 2; ++i) {
            #pragma unroll
            for (int j = 0; j < 4; ++j) {
                int grow = rowbase + w * 32 + i * 16 + ((lane >> 4) << 2) + j;
                if (grow < N) {
                    float2 a = ac2[grow]; float c = a.y > 1.f ? a.y : 1.f;
                    float m = a.x / c;
                    #pragma unroll
                    for (int cf = 0; cf < 8; ++cf) {
                        float v = acc[i][cf][j] + blc[cf] + m * wlc[cf];
                        v = fmaxf(v, 0.f);
                        out[(size_t)grow * 128 + cf * 16 + fr] = (_Float16)v;
                    }
                }
            }
        }
    }
}

// ================= mid mega kernel: enc12 + csr_scatter =================
#define MID_GB  ((NC + 127) / 128)   // 782
#define MID_SC  768

__global__ __launch_bounds__(256)
void k_mid(const _Float16* __restrict__ cxh, const _Float16* __restrict__ Wr1h,
           const _Float16* __restrict__ Wr2h,
           const float* __restrict__ bl1, const float2* __restrict__ ac1,
           const float* __restrict__ Wl1,
           const float* __restrict__ bl2, const float2* __restrict__ ac2,
           const float* __restrict__ Wl2,
           _Float16* __restrict__ out, int N,
           const int* __restrict__ e_cc, int E3,
           int* __restrict__ cursor, int2* __restrict__ se)
{
    __shared__ _Float16 lds[128 * 40 + 128 * 136];
    if (blockIdx.x < MID_GB) {
        enc12_body(lds, blockIdx.x, cxh, Wr1h, Wr2h, bl1, ac1, Wl1, bl2, ac2, Wl2, out, N);
        return;
    }
    int bid = blockIdx.x - MID_GB;
    int t = bid * 256 + threadIdx.x;
    int stride = MID_SC * 256;
    for (int e = t; e < E3; e += stride) {
        int s = e_cc[e], d = e_cc[E3 + e];
        int p = atomicAdd(&cursor[d], 1);
        se[p] = make_int2(s, e);
    }
}

// ---------------- CSR aggregate (fp16 in, fp32 sum, fp16 out), prefetched indices ----------------
__global__ __launch_bounds__(256)
void k_csr_agg_h(const int* __restrict__ off, const int* __restrict__ deg,
                 const int2* __restrict__ se, const _Float16* __restrict__ h,
                 _Float16* __restrict__ agg) {
    int node = (blockIdx.x * blockDim.x + threadIdx.x) >> 6;
    int lane = threadIdx.x & 63;
    if (node >= NC) return;
    int b = off[node], d = deg[node];
    int dm = d < 64 ? d : 64;
    int sj = 0;
    if (lane < dm) sj = se[b + lane].x;
    float sx = 0.f, sy = 0.f;
    #pragma unroll 4
    for (int j = 0; j < dm; ++j) {
        int src = __shfl(sj, j);
        half2v m = *(const half2v*)&h[(size_t)src * 128 + 2 * lane];
        sx += (float)m[0]; sy += (float)m[1];
    }
    for (int j = 64; j < d; ++j) {
        int src = se[b + j].x;
        half2v m = *(const half2v*)&h[(size_t)src * 128 + 2 * lane];
        sx += (float)m[0]; sy += (float)m[1];
    }
    half2v r = {(_Float16)sx, (_Float16)sy};
    *(half2v*)&agg[(size_t)node * 128 + 2 * lane] = r;
}

// ---------------- fused encoder layer 3 + u/v heads ----------------
__global__ __launch_bounds__(256)
void k_enc3uv(const _Float16* __restrict__ aggh, const _Float16* __restrict__ Wl3h,
              const _Float16* __restrict__ cxh, const _Float16* __restrict__ Wr3h,
              const float* __restrict__ bl3, const float* __restrict__ rcnt,
              const _Float16* __restrict__ Wuh, const float* __restrict__ bu,
              const _Float16* __restrict__ Wvh, const float* __restrict__ bv,
              _Float16* __restrict__ uout, _Float16* __restrict__ vout, int N)
{
    __shared__ _Float16 lds[128 * 40 + 128 * 136];
    _Float16* Bh  = lds;
    _Float16* Ah  = lds + 128 * 40;
    _Float16* h3t = lds + 128 * 40;

    const int t = threadIdx.x, lane = t & 63, w = t >> 6;
    const int rowbase = blockIdx.x * 128;
    const bool isA = t < 128;
    const int rr = isA ? t : t - 128;
    const int fr = lane & 15;
    const int kq = (lane >> 4) << 3;

    floatx4 zero4 = {0.f, 0.f, 0.f, 0.f};
    floatx4 acc[2][8];
    #pragma unroll
    for (int i = 0; i < 2; ++i)
        #pragma unroll
        for (int cf = 0; cf < 8; ++cf) acc[i][cf] = zero4;

    float4 p0, p1, p2, p3;
    {
        bool ok = true; const _Float16* base;
        if (isA) { int row = rowbase + rr; ok = row < N; base = ok ? &aggh[(size_t)row * 128] : Ah; }
        else base = &Wl3h[(size_t)rr * 128];
        const float4* s4 = (const float4*)base; float4 zf = make_float4(0.f, 0.f, 0.f, 0.f);
        p0 = ok ? s4[0] : zf; p1 = ok ? s4[1] : zf; p2 = ok ? s4[2] : zf; p3 = ok ? s4[3] : zf;
    }
    for (int tile = 0; tile < 12; ++tile) {
        float4* dst = (float4*)(isA ? &Ah[rr * 40] : &Bh[rr * 40]);
        dst[0] = p0; dst[1] = p1; dst[2] = p2; dst[3] = p3;
        __syncthreads();
        if (tile < 11) {
            int tn = tile + 1;
            bool ok = true; const _Float16* base;
            if (tn < 4) {
                int ko = tn << 5;
                if (isA) { int row = rowbase + rr; ok = row < N; base = ok ? &aggh[(size_t)row * 128 + ko] : Ah; }
                else base = &Wl3h[(size_t)rr * 128 + ko];
            } else {
                int ko = (tn - 4) << 5;
                if (isA) { int row = rowbase + rr; ok = row < N; base = ok ? &cxh[(size_t)row * 256 + ko] : Ah; }
                else base = &Wr3h[(size_t)rr * 256 + ko];
            }
            const float4* s4 = (const float4*)base; float4 zf = make_float4(0.f, 0.f, 0.f, 0.f);
            p0 = ok ? s4[0] : zf; p1 = ok ? s4[1] : zf; p2 = ok ? s4[2] : zf; p3 = ok ? s4[3] : zf;
        }
        half8 af0 = *(const half8*)&Ah[(w * 32 + fr) * 40 + kq];
        half8 af1 = *(const half8*)&Ah[(w * 32 + 16 + fr) * 40 + kq];
        #pragma unroll
        for (int cf = 0; cf < 8; ++cf) {
            half8 bf = *(const half8*)&Bh[(cf * 16 + fr) * 40 + kq];
            acc[0][cf] = __builtin_amdgcn_mfma_f32_16x16x32_f16(af0, bf, acc[0][cf], 0, 0, 0);
            acc[1][cf] = __builtin_amdgcn_mfma_f32_16x16x32_f16(af1, bf, acc[1][cf], 0, 0, 0);
        }
        if (tile == 3) {
            #pragma unroll
            for (int i = 0; i < 2; ++i)
                #pragma unroll
                for (int j = 0; j < 4; ++j) {
                    int row = rowbase + w * 32 + i * 16 + ((lane >> 4) << 2) + j;
                    float c = (row < N) ? rcnt[row] : 1.f;
                    c = c > 1.f ? c : 1.f;
                    float inv = 1.f / c;
                    #pragma unroll
                    for (int cf = 0; cf < 8; ++cf) acc[i][cf][j] *= inv;
                }
        }
        __syncthreads();
    }

    {
        float blc[8];
        #pragma unroll
        for (int cf = 0; cf < 8; ++cf) blc[cf] = bl3[cf * 16 + fr];
        #pragma unroll
        for (int i = 0; i < 2; ++i) {
            #pragma unroll
            for (int j = 0; j < 4; ++j) {
                int lrow = w * 32 + i * 16 + ((lane >> 4) << 2) + j;
                #pragma unroll
                for (int cf = 0; cf < 8; ++cf) {
                    float v = acc[i][cf][j] + blc[cf];
                    v = fmaxf(v, 0.f);
                    h3t[lrow * 136 + cf * 16 + fr] = (_Float16)v;
                }
            }
        }
    }
    __syncthreads();

    for (int ph = 0; ph < 2; ++ph) {
        const _Float16* Wp = ph ? Wvh : Wuh;
        const float* bp = ph ? bv : bu;
        _Float16* op = ph ? vout : uout;
        #pragma unroll
        for (int i = 0; i < 2; ++i)
            #pragma unroll
            for (int cf = 0; cf < 8; ++cf) acc[i][cf] = zero4;
        if (!isA) {
            const float4* s4 = (const float4*)&Wp[(size_t)rr * 128];
            p0 = s4[0]; p1 = s4[1]; p2 = s4[2]; p3 = s4[3];
        }
        for (int tt = 0; tt < 4; ++tt) {
            if (!isA) { float4* dst = (float4*)&Bh[rr * 40]; dst[0] = p0; dst[1] = p1; dst[2] = p2; dst[3] = p3; }
            __syncthreads();
            if (!isA && tt < 3) {
                const float4* s4 = (const float4*)&Wp[(size_t)rr * 128 + ((tt + 1) << 5)];
                p0 = s4[0]; p1 = s4[1]; p2 = s4[2]; p3 = s4[3];
            }
            half8 af0 = *(const half8*)&h3t[(w * 32 + fr) * 136 + (tt << 5) + kq];
            half8 af1 = *(const half8*)&h3t[(w * 32 + 16 + fr) * 136 + (tt << 5) + kq];
            #pragma unroll
            for (int cf = 0; cf < 8; ++cf) {
                half8 bf = *(const half8*)&Bh[(cf * 16 + fr) * 40 + kq];
                acc[0][cf] = __builtin_amdgcn_mfma_f32_16x16x32_f16(af0, bf, acc[0][cf], 0, 0, 0);
                acc[1][cf] = __builtin_amdgcn_mfma_f32_16x16x32_f16(af1, bf, acc[1][cf], 0, 0, 0);
            }
            __syncthreads();
        }
        float bc[8];
        #pragma unroll
        for (int cf = 0; cf < 8; ++cf) bc[cf] = bp[cf * 16 + fr];
        #pragma unroll
        for (int i = 0; i < 2; ++i) {
            #pragma unroll
            for (int j = 0; j < 4; ++j) {
                int grow = rowbase + w * 32 + i * 16 + ((lane >> 4) << 2) + j;
                if (grow < N) {
                    #pragma unroll
                    for (int cf = 0; cf < 8; ++cf)
                        op[(size_t)grow * 128 + cf * 16 + fr] = (_Float16)(acc[i][cf][j] + bc[cf]);
                }
            }
        }
    }
}

// ---------------- decoder over CSR (fp16 u,v), prefetched packed indices ----------------
__global__ __launch_bounds__(256)
void k_decoder_h(const int* __restrict__ off, const int* __restrict__ deg,
                 const int2* __restrict__ se,
                 const _Float16* __restrict__ u, const _Float16* __restrict__ v,
                 const float* __restrict__ wd2, const float* __restrict__ bd2,
                 float* __restrict__ out) {
    int node = (blockIdx.x * blockDim.x + threadIdx.x) >> 6;
    if (node >= NC) return;
    int lane = threadIdx.x & 63;
    int g = lane >> 3, s = lane & 7;

    float wf[16], vf[16];
    #pragma unroll
    for (int q = 0; q < 16; ++q) wf[q] = wd2[s * 16 + q];
    {
        half8 va = *(const half8*)&v[(size_t)node * 128 + s * 16];
        half8 vb = *(const half8*)&v[(size_t)node * 128 + s * 16 + 8];
        #pragma unroll
        for (int q = 0; q < 8; ++q) { vf[q] = (float)va[q]; vf[8 + q] = (float)vb[q]; }
    }
    float bb = bd2[0];

    int b = off[node], d = deg[node];
    int dm = d < 64 ? d : 64;
    int sj = 0, ej = 0;
    if (lane < dm) { int2 p = se[b + lane]; sj = p.x; ej = p.y; }

    for (int jb = 0; jb < d; jb += 8) {
        int j = jb + g;
        float p = 0.f;
        int eid = 0;
        bool act = j < d;
        int src = 0;
        if (jb < 64) {
            src = __shfl(sj, j);
            eid = __shfl(ej, j);
        } else if (act) {
            int2 pr = se[b + j];
            src = pr.x; eid = pr.y;
        }
        if (act) {
            half8 ua = *(const half8*)&u[(size_t)src * 128 + s * 16];
            half8 ub = *(const half8*)&u[(size_t)src * 128 + s * 16 + 8];
            #pragma unroll
            for (int q = 0; q < 8; ++q) {
                p = fmaf(wf[q],     fmaxf((float)ua[q] + vf[q],     0.f), p);
                p = fmaf(wf[8 + q], fmaxf((float)ub[q] + vf[8 + q], 0.f), p);
            }
        }
        p += __shfl_xor(p, 1);
        p += __shfl_xor(p, 2);
        p += __shfl_xor(p, 4);
        if (act && s == 0) out[eid] = p + bb;
    }
}

extern "C" void kernel_launch(void* const* d_in, const int* in_sizes, int n_in,
                              void* d_out, int out_size, void* d_ws, size_t ws_size,
                              hipStream_t stream) {
    const float* article_x = (const float*)d_in[0];
    const float* cx     = (const float*)d_in[1];
    const int*   e_wb   = (const int*)d_in[2];
    const int*   e_mb   = (const int*)d_in[3];
    const int*   e_cc   = (const int*)d_in[4];
    const float* W_lin1 = (const float*)d_in[5];
    const float* b_lin1 = (const float*)d_in[6];
    const float* Wl1    = (const float*)d_in[7];
    const float* bl1    = (const float*)d_in[8];
    const float* Wr1    = (const float*)d_in[9];
    const float* Wl2    = (const float*)d_in[10];
    const float* bl2    = (const float*)d_in[11];
    const float* Wr2    = (const float*)d_in[12];
    const float* Wl3    = (const float*)d_in[13];
    const float* bl3    = (const float*)d_in[14];
    const float* Wr3    = (const float*)d_in[15];
    const float* W_lin2 = (const float*)d_in[16];
    const float* b_lin2 = (const float*)d_in[17];
    const float* Wd1    = (const float*)d_in[18];
    const float* bd1    = (const float*)d_in[19];
    const float* Wd2    = (const float*)d_in[20];
    const float* bd2    = (const float*)d_in[21];
    float* out = (float*)d_out;

    const int E1 = in_sizes[2] / 2;
    const int E2 = in_sizes[3] / 2;
    const int E3 = in_sizes[4] / 2;

    float* ws = (float*)d_ws;
    size_t o = 0;
    float* art   = ws;      o += 1024;
    float* ac1   = ws + o;  o += 2 * NC;   // interleaved (agg,cnt)
    float* ac2   = ws + o;  o += 2 * NC;
    float* cnt3f = ws + o;  o += NC;
    float* buf   = ws + o;  o += 128;
    float* bvf   = ws + o;  o += 128;
    int* deg    = (int*)(ws + o); o += NC;
    int* pre    = (int*)(ws + o); o += NC;
    int* off    = (int*)(ws + o); o += NC;
    int* cursor = (int*)(ws + o); o += NC;
    int* blksum = (int*)(ws + o); o += 256;
    int2* se    = (int2*)(ws + o); o += 2 * 800000;
    _Float16* hws = (_Float16*)(ws + o);
    size_t ho = 0;
    _Float16* cxh    = hws + ho; ho += (size_t)NC * 256;
    _Float16* B1h    = hws + ho; ho += (size_t)NC * 128;
    _Float16* B2h    = hws + ho; ho += (size_t)NC * 128;
    _Float16* Wr1h   = hws + ho; ho += 128 * 256;
    _Float16* Wr2h   = hws + ho; ho += 128 * 128;
    _Float16* Wl3h   = hws + ho; ho += 128 * 128;
    _Float16* Wr3h   = hws + ho; ho += 128 * 256;
    _Float16* Wuh    = hws + ho; ho += 128 * 128;
    _Float16* Wvh    = hws + ho; ho += 128 * 128;

    hipMemsetAsync(ac1, 0, 4 * NC * sizeof(float), stream);   // ac1 + ac2
    hipMemsetAsync(deg, 0, NC * sizeof(int), stream);

    k_art<<<256, 256, 0, stream>>>(article_x, W_lin1, b_lin1, art);

    // mega front: edges(wb,mb) + hist(cc) + weight cvts + wcomb/bcomb + cvt(cx)
    k_front<<<FRONT_TOTAL, 256, 0, stream>>>(
        e_wb, E1, e_mb, E2, e_cc, E3, art, ac1, ac2, deg,
        Wr1, Wr1h, Wr2, Wr2h, Wl3, Wl3h, Wr3, Wr3h,
        Wd1, W_lin2, Wuh, Wvh, b_lin2, bd1, buf, bvf, cx, cxh);

    const int NB = (NC + 1023) / 1024;  // 98
    k_scan1<<<NB, 256, 0, stream>>>(deg, pre, blksum);
    k_scan2<<<1, 256, 0, stream>>>(blksum, NB);
    k_scan3<<<(NC + 255) / 256, 256, 0, stream>>>(pre, blksum, deg, off, cursor, cnt3f);

    // mega mid: enc12 GEMM + csr scatter (independent, overlap)
    k_mid<<<MID_GB + MID_SC, 256, 0, stream>>>(
        cxh, Wr1h, Wr2h, bl1, (const float2*)ac1, Wl1, bl2, (const float2*)ac2, Wl2,
        B1h, NC, e_cc, E3, cursor, se);

    const int GW = (NC * 64 + 255) / 256;  // 1 wave per node
    k_csr_agg_h<<<GW, 256, 0, stream>>>(off, deg, se, B1h, B2h);
    k_enc3uv<<<MID_GB, 256, 0, stream>>>(B2h, Wl3h, cxh, Wr3h,
                                         bl3, cnt3f, Wuh, buf, Wvh, bvf,
                                         B1h, B2h, NC);
    k_decoder_h<<<GW, 256, 0, stream>>>(off, deg, se, B1h, B2h, Wd2, bd2, out);
}